// Round 3
// baseline (406.911 us; speedup 1.0000x reference)
//
#include <hip/hip_runtime.h>
#include <hip/hip_bf16.h>

#define NH 8
#define SQ 2048
#define HD 64
#define NTOT (NH * SQ * HD)   // 1048576
#define PIT 72                 // LDS row pitch in u16 (epi kernel only)

typedef unsigned short u16;
typedef unsigned int u32;
typedef __attribute__((ext_vector_type(8))) unsigned short us8;
typedef __attribute__((ext_vector_type(4))) unsigned short us4v;
typedef __attribute__((ext_vector_type(8))) _Float16 h8;   // MFMA f16 A/B fragment
typedef __attribute__((ext_vector_type(4))) float f4;      // MFMA C/D fragment
typedef __attribute__((ext_vector_type(4))) u32 u4;

#define MFMA_F16 __builtin_amdgcn_mfma_f32_16x16x32_f16

__device__ __forceinline__ u16 f2h(float f) {
    union { _Float16 h; u16 u; } c; c.h = (_Float16)f; return c.u;
}
__device__ __forceinline__ float h2f(u16 u) {
    union { _Float16 h; u16 u; } c; c.u = u; return (float)c.h;
}
__device__ __forceinline__ h8 neg_h8(h8 a) {
    union { h8 h; u4 u; } c; c.h = a;
    c.u ^= 0x80008000u;
    return c.h;
}
// 8 contiguous f32 -> f16x8 fragment (two float4 loads, hw cvt)
__device__ __forceinline__ h8 pack8h(const float* p) {
    float4 a = ((const float4*)p)[0];
    float4 b = ((const float4*)p)[1];
    h8 r;
    r[0] = (_Float16)a.x; r[1] = (_Float16)a.y; r[2] = (_Float16)a.z; r[3] = (_Float16)a.w;
    r[4] = (_Float16)b.x; r[5] = (_Float16)b.y; r[6] = (_Float16)b.z; r[7] = (_Float16)b.w;
    return r;
}

// T2 swizzle (Pb only now): pitch 64 u16, 16B-chunk index XOR'd with row&7.
__device__ __forceinline__ int swz8(int row, int chunk) {   // u16 offset of 8-u16 chunk
    return row * 64 + ((chunk ^ (row & 7)) << 3);
}

struct Afrag { h8 r0, r1, i0, i1, ni0, ni1; };

// ---------------------------------------------------------------------------
// Kernel 1: MFMA complex projections (unchanged).
// ---------------------------------------------------------------------------
__global__ __launch_bounds__(256) void proj_kernel(
    const float* __restrict__ q_r, const float* __restrict__ q_i,
    const float* __restrict__ k_r, const float* __restrict__ k_i,
    const float* __restrict__ v_r, const float* __restrict__ v_i,
    const float* __restrict__ pe_q_r, const float* __restrict__ pe_q_i,
    const float* __restrict__ pe_k_r, const float* __restrict__ pe_k_i,
    const float* __restrict__ qwr, const float* __restrict__ qwi,
    const float* __restrict__ qbr, const float* __restrict__ qbi,
    const float* __restrict__ kwr, const float* __restrict__ kwi,
    const float* __restrict__ kbr, const float* __restrict__ kbi,
    const float* __restrict__ vwr, const float* __restrict__ vwi,
    const float* __restrict__ vbr, const float* __restrict__ vbi,
    const float* __restrict__ gwr, const float* __restrict__ gwi,
    const float* __restrict__ gbr, const float* __restrict__ gbi,
    u16* __restrict__ q1r, u16* __restrict__ q1i,
    u16* __restrict__ q2r, u16* __restrict__ q2i,
    u16* __restrict__ kpr, u16* __restrict__ kpi,
    u16* __restrict__ vtr, u16* __restrict__ vti,
    float* __restrict__ out_gr, float* __restrict__ out_gi)
{
    const int t = threadIdx.x;
    const int wv = t >> 6, l = t & 63;
    const int quad = l >> 4, m16 = l & 15;
    const int rowbase = blockIdx.x * 16;
    const int arow = rowbase + m16;
    const int h = rowbase >> 11;
    const int c0 = quad * 8;

    auto loadA = [&](const float* pr, const float* pi) {
        Afrag a;
        const float* rp = pr + arow * 64;
        const float* ip = pi + arow * 64;
        a.r0 = pack8h(rp + c0);      a.r1 = pack8h(rp + 32 + c0);
        a.i0 = pack8h(ip + c0);      a.i1 = pack8h(ip + 32 + c0);
        a.ni0 = neg_h8(a.i0);        a.ni1 = neg_h8(a.i1);
        return a;
    };

    auto ctile = [&](const Afrag& A, const float* wr, const float* wi, int cb,
                     f4& Cr, f4& Ci) {
        const float* wrp = wr + (cb + m16) * 64;
        const float* wip = wi + (cb + m16) * 64;
        h8 Br0 = pack8h(wrp + c0), Br1 = pack8h(wrp + 32 + c0);
        h8 Bi0 = pack8h(wip + c0), Bi1 = pack8h(wip + 32 + c0);
        Cr = (f4)0.f; Ci = (f4)0.f;
        Cr = MFMA_F16(A.r0,  Br0, Cr, 0, 0, 0);
        Cr = MFMA_F16(A.r1,  Br1, Cr, 0, 0, 0);
        Cr = MFMA_F16(A.ni0, Bi0, Cr, 0, 0, 0);
        Cr = MFMA_F16(A.ni1, Bi1, Cr, 0, 0, 0);
        Ci = MFMA_F16(A.r0,  Bi0, Ci, 0, 0, 0);
        Ci = MFMA_F16(A.r1,  Bi1, Ci, 0, 0, 0);
        Ci = MFMA_F16(A.i0,  Br0, Ci, 0, 0, 0);
        Ci = MFMA_F16(A.i1,  Br1, Ci, 0, 0, 0);
    };

    auto qtile = [&](const Afrag& A, int nt) {
        f4 Cr, Ci;
        ctile(A, qwr, qwi, nt * 16, Cr, Ci);
        int c = nt * 16 + m16;
        float br = qbr[c], bi = qbi[c];
        int dd = c >> 1, pc = c & 63;
        u16* dR = (c & 1) ? q2r : q1r;
        u16* dI = (c & 1) ? q2i : q1i;
        #pragma unroll
        for (int r = 0; r < 4; ++r) {
            int g = rowbase + quad * 4 + r;
            dR[g * 64 + dd] = f2h(Cr[r] + br + pe_q_r[g * 64 + pc]);
            dI[g * 64 + dd] = f2h(Ci[r] + bi + pe_q_i[g * 64 + pc]);
        }
    };
    auto ktile = [&](const Afrag& A, int nt) {
        f4 Cr, Ci;
        ctile(A, kwr, kwi, nt * 16, Cr, Ci);
        int c = nt * 16 + m16;
        float br = kbr[c], bi = kbi[c];
        #pragma unroll
        for (int r = 0; r < 4; ++r) {
            int g = rowbase + quad * 4 + r;
            kpr[g * 64 + c] = f2h(Cr[r] + br + pe_k_r[g * 64 + c]);
            kpi[g * 64 + c] = f2h(Ci[r] + bi + pe_k_i[g * 64 + c]);
        }
    };
    auto vtile = [&](const Afrag& A, int nt) {
        f4 Cr, Ci;
        ctile(A, vwr, vwi, nt * 16, Cr, Ci);
        int c = nt * 16 + m16;
        float br = vbr[c], bi = vbi[c];
        int s0 = (rowbase & 2047) + quad * 4;
        size_t tix = (size_t)(h * 64 + c) * 2048 + s0;
        us4v pr, pi;
        #pragma unroll
        for (int r = 0; r < 4; ++r) {
            pr[r] = f2h(Cr[r] + br);
            pi[r] = f2h(Ci[r] + bi);
        }
        *(us4v*)&vtr[tix] = pr;
        *(us4v*)&vti[tix] = pi;
    };
    auto gtile = [&](const Afrag& A, int nt) {
        f4 Cr, Ci;
        ctile(A, gwr, gwi, nt * 16, Cr, Ci);
        int c = nt * 16 + m16;
        float br = gbr[c], bi = gbi[c];
        #pragma unroll
        for (int r = 0; r < 4; ++r) {
            int g = rowbase + quad * 4 + r;
            out_gr[g * 64 + c] = Cr[r] + br;
            out_gi[g * 64 + c] = Ci[r] + bi;
        }
    };

    if (wv == 0) {
        Afrag Aq = loadA(q_r, q_i);
        qtile(Aq, 0); qtile(Aq, 1); qtile(Aq, 2); qtile(Aq, 3); qtile(Aq, 4);
    } else if (wv == 1) {
        Afrag Aq = loadA(q_r, q_i);
        qtile(Aq, 5); qtile(Aq, 6); qtile(Aq, 7);
        gtile(Aq, 0); gtile(Aq, 1);
    } else if (wv == 2) {
        Afrag Ak = loadA(k_r, k_i);
        ktile(Ak, 0); ktile(Ak, 1); ktile(Ak, 2); ktile(Ak, 3);
        Afrag Aq = loadA(q_r, q_i);
        gtile(Aq, 2);
    } else {
        Afrag Av = loadA(v_r, v_i);
        vtile(Av, 0); vtile(Av, 1); vtile(Av, 2); vtile(Av, 3);
        Afrag Aq = loadA(q_r, q_i);
        gtile(Aq, 3);
    }
}

// ---------------------------------------------------------------------------
// Kernel 2: MFMA flash attention, barrier-free.
//   Round-11 change: K/V LDS staging DELETED. B-fragments are loaded
//   directly from global (L1/L2-resident: K+V per head = 1MB, per-kt hot
//   set 32KB ~ L1). This moves ~64us of DS-pipe occupancy (34 ds_read_b128
//   per wave-iter at 85B/cyc) onto the parallel TA/L1 path and removes
//   BOTH __syncthreads per kt (Pb is wave-private: each wave writes/reads
//   only its own 16-row stripe -> lgkmcnt ordering suffices).
// ---------------------------------------------------------------------------
__global__ __launch_bounds__(256) void attn_kernel(
    const u16* __restrict__ q1r, const u16* __restrict__ q1i,
    const u16* __restrict__ q2r, const u16* __restrict__ q2i,
    const u16* __restrict__ kpr, const u16* __restrict__ kpi,
    const u16* __restrict__ vtr, const u16* __restrict__ vti,
    u16* __restrict__ o1r, u16* __restrict__ o1i,
    u16* __restrict__ o2r, u16* __restrict__ o2i)
{
    __shared__ __align__(16) u16 Pb[64 * 64];   // P staging only (8KB)

    const int t  = threadIdx.x;
    const int qt = blockIdx.x;
    const int br = blockIdx.y;
    const int h  = blockIdx.z;

    const int wq   = t >> 6;
    const int l    = t & 63;
    const int quad = l >> 4;
    const int m    = l & 15;

    const u16* Qsr = br ? q2r : q1r;
    const u16* Qsi = br ? q2i : q1i;
    const int hbase = h * SQ * 64;
    const int qbase = hbase + qt * 64 * 64;
    const int vbase = h * 64 * SQ;

    const u16* qrr = Qsr + qbase + (wq * 16 + m) * 64;
    const u16* qri = Qsi + qbase + (wq * 16 + m) * 64;
    h8 Qr0 = *(const h8*)(qrr + quad * 8);
    h8 Qr1 = *(const h8*)(qrr + 32 + quad * 8);
    h8 Qi0 = *(const h8*)(qri + quad * 8);
    h8 Qi1 = *(const h8*)(qri + 32 + quad * 8);
    h8 nQr0 = neg_h8(Qr0);
    h8 nQr1 = neg_h8(Qr1);

    // B-side base pointers, advanced per kt.
    // K fragment rows nt*16+m, cols quad*8 (+32);  V rows dt*16+m, s = kt*64+quad*8 (+32)
    const u16* bKr = kpr + hbase + m * 64 + quad * 8;   // += 4096 per kt
    const u16* bKi = kpi + hbase + m * 64 + quad * 8;
    const u16* bVr = vtr + vbase + m * 2048 + quad * 8; // += 64 per kt
    const u16* bVi = vti + vbase + m * 2048 + quad * 8;

    float mreg[4], Lp[4];
    #pragma unroll
    for (int r = 0; r < 4; ++r) { mreg[r] = -1e30f; Lp[r] = 0.f; }
    f4 Ovr[4], Ovi[4];
    #pragma unroll
    for (int d = 0; d < 4; ++d) { Ovr[d] = (f4)0.f; Ovi[d] = (f4)0.f; }

    for (int kt = 0; kt < 32; ++kt) {
        // ---- QK^T (complex magnitude scores), B-frags straight from global ----
        float sv[4][4];
        #pragma unroll
        for (int nt = 0; nt < 4; ++nt) {
            h8 k0 = *(const h8*)(bKr + nt * 1024);
            h8 k1 = *(const h8*)(bKr + nt * 1024 + 32);
            h8 c0 = *(const h8*)(bKi + nt * 1024);
            h8 c1 = *(const h8*)(bKi + nt * 1024 + 32);
            f4 ar = (f4)0.f, ai = (f4)0.f;
            __builtin_amdgcn_s_setprio(1);
            ar = MFMA_F16(Qr0, k0, ar, 0, 0, 0);
            ar = MFMA_F16(Qr1, k1, ar, 0, 0, 0);
            ar = MFMA_F16(Qi0, c0, ar, 0, 0, 0);
            ar = MFMA_F16(Qi1, c1, ar, 0, 0, 0);
            ai = MFMA_F16(Qi0, k0, ai, 0, 0, 0);
            ai = MFMA_F16(Qi1, k1, ai, 0, 0, 0);
            ai = MFMA_F16(nQr0, c0, ai, 0, 0, 0);
            ai = MFMA_F16(nQr1, c1, ai, 0, 0, 0);
            __builtin_amdgcn_s_setprio(0);
            #pragma unroll
            for (int r = 0; r < 4; ++r)
                sv[nt][r] = __builtin_amdgcn_sqrtf(ar[r] * ar[r] + ai[r] * ai[r] + 1e-8f) * 0.125f;
        }
        bKr += 4096; bKi += 4096;

        // ---- exact per-row tile max (16-lane reduce) ----
        float rv[4];
        #pragma unroll
        for (int r = 0; r < 4; ++r) {
            float x = fmaxf(fmaxf(sv[0][r], sv[1][r]), fmaxf(sv[2][r], sv[3][r]));
            x = fmaxf(x, __shfl_xor(x, 1));
            x = fmaxf(x, __shfl_xor(x, 2));
            x = fmaxf(x, __shfl_xor(x, 4));
            x = fmaxf(x, __shfl_xor(x, 8));
            rv[r] = x;
        }

        // ---- T13 defer-max: rescale only when a row grows past slack ----
        bool need = (rv[0] > mreg[0] + 8.f) | (rv[1] > mreg[1] + 8.f) |
                    (rv[2] > mreg[2] + 8.f) | (rv[3] > mreg[3] + 8.f);
        if (__any(need)) {
            #pragma unroll
            for (int r = 0; r < 4; ++r) {
                float mn = fmaxf(mreg[r], rv[r]);
                float al = __expf(mreg[r] - mn);
                mreg[r] = mn;
                Lp[r] *= al;
                #pragma unroll
                for (int dtr = 0; dtr < 4; ++dtr) { Ovr[dtr][r] *= al; Ovi[dtr][r] *= al; }
            }
        }

        // ---- P = exp(s - m)  (f32 row-sum partials; f16 to LDS for MFMA) ----
        #pragma unroll
        for (int r = 0; r < 4; ++r) {
            const int prow = wq * 16 + quad * 4 + r;
            #pragma unroll
            for (int nt = 0; nt < 4; ++nt) {
                float p = __expf(sv[nt][r] - mreg[r]);
                Lp[r] += p;
                const int col = nt * 16 + m;
                Pb[swz8(prow, col >> 3) + (col & 7)] = f2h(p);
            }
        }

        const int qrow = wq * 16 + m;
        h8 pa0 = *(const h8*)&Pb[swz8(qrow, quad)];
        h8 pa1 = *(const h8*)&Pb[swz8(qrow, quad + 4)];

        // ---- PV, V-frags straight from global ----
        #pragma unroll
        for (int dt = 0; dt < 4; ++dt) {
            h8 b0 = *(const h8*)(bVr + dt * 32768);
            h8 b1 = *(const h8*)(bVr + dt * 32768 + 32);
            h8 d0 = *(const h8*)(bVi + dt * 32768);
            h8 d1 = *(const h8*)(bVi + dt * 32768 + 32);
            __builtin_amdgcn_s_setprio(1);
            Ovr[dt] = MFMA_F16(pa0, b0, Ovr[dt], 0, 0, 0);
            Ovr[dt] = MFMA_F16(pa1, b1, Ovr[dt], 0, 0, 0);
            Ovi[dt] = MFMA_F16(pa0, d0, Ovi[dt], 0, 0, 0);
            Ovi[dt] = MFMA_F16(pa1, d1, Ovi[dt], 0, 0, 0);
            __builtin_amdgcn_s_setprio(0);
        }
        bVr += 64; bVi += 64;
    }

    {
        // finish L: reduce partials across the 16 m-lanes
        #pragma unroll
        for (int r = 0; r < 4; ++r) {
            float x = Lp[r];
            x += __shfl_xor(x, 1);
            x += __shfl_xor(x, 2);
            x += __shfl_xor(x, 4);
            x += __shfl_xor(x, 8);
            Lp[r] = x;
        }
        u16* Dr = br ? o2r : o1r;
        u16* Di = br ? o2i : o1i;
        float inv[4];
        #pragma unroll
        for (int r = 0; r < 4; ++r) inv[r] = 1.f / Lp[r];
        #pragma unroll
        for (int dt = 0; dt < 4; ++dt) {
            #pragma unroll
            for (int r = 0; r < 4; ++r) {
                int q = wq * 16 + quad * 4 + r;
                Dr[qbase + q * 64 + dt * 16 + m] = f2h(Ovr[dt][r] * inv[r]);
                Di[qbase + q * 64 + dt * 16 + m] = f2h(Ovi[dt][r] * inv[r]);
            }
        }
    }
}

// ---------------------------------------------------------------------------
// Kernel 3: MFMA epilogue (unchanged).
// ---------------------------------------------------------------------------
__global__ __launch_bounds__(256) void epi_kernel(
    const u16* __restrict__ o1r, const u16* __restrict__ o1i,
    const u16* __restrict__ o2r, const u16* __restrict__ o2i,
    const float* __restrict__ out_gr, const float* __restrict__ out_gi,
    const float* __restrict__ subw,
    const float* __restrict__ owr, const float* __restrict__ owi,
    const float* __restrict__ obr, const float* __restrict__ obi,
    float* __restrict__ out_r, float* __restrict__ out_i)
{
    __shared__ __align__(16) u16 L1r[16][64], L1i[16][64];
    __shared__ __align__(16) u16 L2r[16][64], L2i[16][64];
    __shared__ __align__(16) u16 Xr[16][PIT], Xi[16][PIT];

    const int t = threadIdx.x;
    const int rowbase = blockIdx.x * 16;

    // ---- stage o1/o2 (coalesced 8B loads) ----
    {
        int r = t >> 4, c4 = (t & 15) * 4;
        size_t gi = (size_t)(rowbase + r) * 64 + c4;
        *(us4v*)&L1r[r][c4] = *(const us4v*)(o1r + gi);
        *(us4v*)&L1i[r][c4] = *(const us4v*)(o1i + gi);
        *(us4v*)&L2r[r][c4] = *(const us4v*)(o2r + gi);
        *(us4v*)&L2i[r][c4] = *(const us4v*)(o2i + gi);
    }
    __syncthreads();

    // ---- RMS (joint over o1,o2 = all 128 interleaved cols) + x ----
    {
        int r = t >> 4, c4 = (t & 15) * 4;
        float ss = 0.f;
        #pragma unroll
        for (int j = 0; j < 4; ++j) {
            float a = h2f(L1r[r][c4 + j]), b = h2f(L1i[r][c4 + j]);
            float c = h2f(L2r[r][c4 + j]), d = h2f(L2i[r][c4 + j]);
            ss += a * a + b * b + c * c + d * d;
        }
        ss += __shfl_xor(ss, 1);
        ss += __shfl_xor(ss, 2);
        ss += __shfl_xor(ss, 4);
        ss += __shfl_xor(ss, 8);
        float inv = 1.f / sqrtf(ss * (1.f / 128.f) + 1e-5f);

        float4 g_r = *(const float4*)(out_gr + (size_t)(rowbase + r) * 64 + c4);
        float4 g_i = *(const float4*)(out_gi + (size_t)(rowbase + r) * 64 + c4);
        const float* grv = (const float*)&g_r;
        const float* giv = (const float*)&g_i;

        us4v xrp, xip;
        #pragma unroll
        for (int j = 0; j < 4; ++j) {
            int c = c4 + j;
            int s = c >> 1;
            float cr_ = (c & 1) ? h2f(L2r[r][s]) : h2f(L1r[r][s]);
            float ci_ = (c & 1) ? h2f(L2i[r][s]) : h2f(L1i[r][s]);
            float sw = subw[c];
            float ar_ = cr_ * inv * sw;
            float ai_ = ci_ * inv * sw;
            xrp[j] = f2h(grv[j] * ar_ - giv[j] * ai_);
            xip[j] = f2h(grv[j] * ai_ + giv[j] * ar_);
        }
        *(us4v*)&Xr[r][c4] = xrp;
        *(us4v*)&Xi[r][c4] = xip;
    }
    __syncthreads();

    // ---- out-projection: wave w = n-tile w ----
    const int wv = t >> 6, l = t & 63;
    const int quad = l >> 4, m16 = l & 15;
    const int c0 = quad * 8;

    h8 Ar0 = *(const h8*)&Xr[m16][c0];
    h8 Ar1 = *(const h8*)&Xr[m16][32 + c0];
    h8 Ai0 = *(const h8*)&Xi[m16][c0];
    h8 Ai1 = *(const h8*)&Xi[m16][32 + c0];
    h8 nAi0 = neg_h8(Ai0), nAi1 = neg_h8(Ai1);

    const int c = wv * 16 + m16;
    const float* wrp = owr + c * 64;
    const float* wip = owi + c * 64;
    h8 Br0 = pack8h(wrp + c0), Br1 = pack8h(wrp + 32 + c0);
    h8 Bi0 = pack8h(wip + c0), Bi1 = pack8h(wip + 32 + c0);

    f4 Cr = (f4)0.f, Ci = (f4)0.f;
    Cr = MFMA_F16(Ar0,  Br0, Cr, 0, 0, 0);
    Cr = MFMA_F16(Ar1,  Br1, Cr, 0, 0, 0);
    Cr = MFMA_F16(nAi0, Bi0, Cr, 0, 0, 0);
    Cr = MFMA_F16(nAi1, Bi1, Cr, 0, 0, 0);
    Ci = MFMA_F16(Ar0,  Bi0, Ci, 0, 0, 0);
    Ci = MFMA_F16(Ar1,  Bi1, Ci, 0, 0, 0);
    Ci = MFMA_F16(Ai0,  Br0, Ci, 0, 0, 0);
    Ci = MFMA_F16(Ai1,  Br1, Ci, 0, 0, 0);

    float br_ = obr[c], bi_ = obi[c];
    #pragma unroll
    for (int r = 0; r < 4; ++r) {
        size_t g = (size_t)(rowbase + quad * 4 + r) * 64 + c;
        out_r[g] = Cr[r] + br_;
        out_i[g] = Ci[r] + bi_;
    }
}

// ---------------------------------------------------------------------------
extern "C" void kernel_launch(void* const* d_in, const int* in_sizes, int n_in,
                              void* d_out, int out_size, void* d_ws, size_t ws_size,
                              hipStream_t stream)
{
    (void)in_sizes; (void)n_in; (void)out_size; (void)ws_size;

    float* out    = (float*)d_out;
    float* out_r  = out;
    float* out_i  = out + (size_t)NTOT;
    float* out_gr = out + 2 * (size_t)NTOT;
    float* out_gi = out + 3 * (size_t)NTOT;

    // workspace layout (f16 only), 24 MB total
    char* w = (char*)d_ws;
    const size_t N = (size_t)NTOT;
    u16* q1r = (u16*)w; w += N * 2;
    u16* q1i = (u16*)w; w += N * 2;
    u16* q2r = (u16*)w; w += N * 2;
    u16* q2i = (u16*)w; w += N * 2;
    u16* kpr = (u16*)w; w += N * 2;
    u16* kpi = (u16*)w; w += N * 2;
    u16* vtr = (u16*)w; w += N * 2;   // [h][d][s]
    u16* vti = (u16*)w; w += N * 2;   // [h][d][s]
    u16* o1r = (u16*)w; w += N * 2;
    u16* o1i = (u16*)w; w += N * 2;
    u16* o2r = (u16*)w; w += N * 2;
    u16* o2i = (u16*)w; w += N * 2;

    proj_kernel<<<dim3(1024), dim3(256), 0, stream>>>(
        (const float*)d_in[0], (const float*)d_in[1],
        (const float*)d_in[2], (const float*)d_in[3],
        (const float*)d_in[4], (const float*)d_in[5],
        (const float*)d_in[6], (const float*)d_in[7],
        (const float*)d_in[8], (const float*)d_in[9],
        (const float*)d_in[10], (const float*)d_in[11],
        (const float*)d_in[12], (const float*)d_in[13],
        (const float*)d_in[14], (const float*)d_in[15],
        (const float*)d_in[16], (const float*)d_in[17],
        (const float*)d_in[18], (const float*)d_in[19],
        (const float*)d_in[20], (const float*)d_in[21],
        (const float*)d_in[22], (const float*)d_in[23],
        (const float*)d_in[24], (const float*)d_in[25],
        q1r, q1i, q2r, q2i, kpr, kpi, vtr, vti, out_gr, out_gi);

    attn_kernel<<<dim3(SQ / 64, 2, NH), dim3(256), 0, stream>>>(
        q1r, q1i, q2r, q2i, kpr, kpi, vtr, vti, o1r, o1i, o2r, o2i);

    epi_kernel<<<dim3(1024), dim3(256), 0, stream>>>(
        o1r, o1i, o2r, o2i, out_gr, out_gi,
        (const float*)d_in[34], (const float*)d_in[26], (const float*)d_in[27],
        (const float*)d_in[28], (const float*)d_in[29],
        out_r, out_i);
}

// Round 4
// 294.120 us; speedup vs baseline: 1.3835x; 1.3835x over previous
//
#include <hip/hip_runtime.h>
#include <hip/hip_bf16.h>

#define NH 8
#define SQ 2048
#define HD 64
#define NTOT (NH * SQ * HD)   // 1048576
#define PIT 72                 // LDS row pitch in u16 (epi kernel only)

typedef unsigned short u16;
typedef unsigned int u32;
typedef __attribute__((ext_vector_type(8))) unsigned short us8;
typedef __attribute__((ext_vector_type(4))) unsigned short us4v;
typedef __attribute__((ext_vector_type(8))) _Float16 h8;   // MFMA f16 A/B fragment
typedef __attribute__((ext_vector_type(4))) float f4;      // MFMA C/D fragment
typedef __attribute__((ext_vector_type(4))) u32 u4;

#define MFMA_F16 __builtin_amdgcn_mfma_f32_16x16x32_f16

__device__ __forceinline__ u16 f2h(float f) {
    union { _Float16 h; u16 u; } c; c.h = (_Float16)f; return c.u;
}
__device__ __forceinline__ float h2f(u16 u) {
    union { _Float16 h; u16 u; } c; c.u = u; return (float)c.h;
}
__device__ __forceinline__ h8 neg_h8(h8 a) {
    union { h8 h; u4 u; } c; c.h = a;
    c.u ^= 0x80008000u;
    return c.h;
}
// 8 contiguous f32 -> f16x8 fragment (two float4 loads, hw cvt)
__device__ __forceinline__ h8 pack8h(const float* p) {
    float4 a = ((const float4*)p)[0];
    float4 b = ((const float4*)p)[1];
    h8 r;
    r[0] = (_Float16)a.x; r[1] = (_Float16)a.y; r[2] = (_Float16)a.z; r[3] = (_Float16)a.w;
    r[4] = (_Float16)b.x; r[5] = (_Float16)b.y; r[6] = (_Float16)b.z; r[7] = (_Float16)b.w;
    return r;
}

// T2 swizzle: pitch 64 u16 (128B rows), 16B-chunk index XOR'd with row&7.
__device__ __forceinline__ int swz8(int row, int chunk) {   // u16 offset of 8-u16 chunk
    return row * 64 + ((chunk ^ (row & 7)) << 3);
}

struct Afrag { h8 r0, r1, i0, i1, ni0, ni1; };

// ---------------------------------------------------------------------------
// Kernel 1: MFMA complex projections (unchanged).
// ---------------------------------------------------------------------------
__global__ __launch_bounds__(256) void proj_kernel(
    const float* __restrict__ q_r, const float* __restrict__ q_i,
    const float* __restrict__ k_r, const float* __restrict__ k_i,
    const float* __restrict__ v_r, const float* __restrict__ v_i,
    const float* __restrict__ pe_q_r, const float* __restrict__ pe_q_i,
    const float* __restrict__ pe_k_r, const float* __restrict__ pe_k_i,
    const float* __restrict__ qwr, const float* __restrict__ qwi,
    const float* __restrict__ qbr, const float* __restrict__ qbi,
    const float* __restrict__ kwr, const float* __restrict__ kwi,
    const float* __restrict__ kbr, const float* __restrict__ kbi,
    const float* __restrict__ vwr, const float* __restrict__ vwi,
    const float* __restrict__ vbr, const float* __restrict__ vbi,
    const float* __restrict__ gwr, const float* __restrict__ gwi,
    const float* __restrict__ gbr, const float* __restrict__ gbi,
    u16* __restrict__ q1r, u16* __restrict__ q1i,
    u16* __restrict__ q2r, u16* __restrict__ q2i,
    u16* __restrict__ kpr, u16* __restrict__ kpi,
    u16* __restrict__ vtr, u16* __restrict__ vti,
    float* __restrict__ out_gr, float* __restrict__ out_gi)
{
    const int t = threadIdx.x;
    const int wv = t >> 6, l = t & 63;
    const int quad = l >> 4, m16 = l & 15;
    const int rowbase = blockIdx.x * 16;
    const int arow = rowbase + m16;
    const int h = rowbase >> 11;
    const int c0 = quad * 8;

    auto loadA = [&](const float* pr, const float* pi) {
        Afrag a;
        const float* rp = pr + arow * 64;
        const float* ip = pi + arow * 64;
        a.r0 = pack8h(rp + c0);      a.r1 = pack8h(rp + 32 + c0);
        a.i0 = pack8h(ip + c0);      a.i1 = pack8h(ip + 32 + c0);
        a.ni0 = neg_h8(a.i0);        a.ni1 = neg_h8(a.i1);
        return a;
    };

    auto ctile = [&](const Afrag& A, const float* wr, const float* wi, int cb,
                     f4& Cr, f4& Ci) {
        const float* wrp = wr + (cb + m16) * 64;
        const float* wip = wi + (cb + m16) * 64;
        h8 Br0 = pack8h(wrp + c0), Br1 = pack8h(wrp + 32 + c0);
        h8 Bi0 = pack8h(wip + c0), Bi1 = pack8h(wip + 32 + c0);
        Cr = (f4)0.f; Ci = (f4)0.f;
        Cr = MFMA_F16(A.r0,  Br0, Cr, 0, 0, 0);
        Cr = MFMA_F16(A.r1,  Br1, Cr, 0, 0, 0);
        Cr = MFMA_F16(A.ni0, Bi0, Cr, 0, 0, 0);
        Cr = MFMA_F16(A.ni1, Bi1, Cr, 0, 0, 0);
        Ci = MFMA_F16(A.r0,  Bi0, Ci, 0, 0, 0);
        Ci = MFMA_F16(A.r1,  Bi1, Ci, 0, 0, 0);
        Ci = MFMA_F16(A.i0,  Br0, Ci, 0, 0, 0);
        Ci = MFMA_F16(A.i1,  Br1, Ci, 0, 0, 0);
    };

    auto qtile = [&](const Afrag& A, int nt) {
        f4 Cr, Ci;
        ctile(A, qwr, qwi, nt * 16, Cr, Ci);
        int c = nt * 16 + m16;
        float br = qbr[c], bi = qbi[c];
        int dd = c >> 1, pc = c & 63;
        u16* dR = (c & 1) ? q2r : q1r;
        u16* dI = (c & 1) ? q2i : q1i;
        #pragma unroll
        for (int r = 0; r < 4; ++r) {
            int g = rowbase + quad * 4 + r;
            dR[g * 64 + dd] = f2h(Cr[r] + br + pe_q_r[g * 64 + pc]);
            dI[g * 64 + dd] = f2h(Ci[r] + bi + pe_q_i[g * 64 + pc]);
        }
    };
    auto ktile = [&](const Afrag& A, int nt) {
        f4 Cr, Ci;
        ctile(A, kwr, kwi, nt * 16, Cr, Ci);
        int c = nt * 16 + m16;
        float br = kbr[c], bi = kbi[c];
        #pragma unroll
        for (int r = 0; r < 4; ++r) {
            int g = rowbase + quad * 4 + r;
            kpr[g * 64 + c] = f2h(Cr[r] + br + pe_k_r[g * 64 + c]);
            kpi[g * 64 + c] = f2h(Ci[r] + bi + pe_k_i[g * 64 + c]);
        }
    };
    auto vtile = [&](const Afrag& A, int nt) {
        f4 Cr, Ci;
        ctile(A, vwr, vwi, nt * 16, Cr, Ci);
        int c = nt * 16 + m16;
        float br = vbr[c], bi = vbi[c];
        int s0 = (rowbase & 2047) + quad * 4;
        size_t tix = (size_t)(h * 64 + c) * 2048 + s0;
        us4v pr, pi;
        #pragma unroll
        for (int r = 0; r < 4; ++r) {
            pr[r] = f2h(Cr[r] + br);
            pi[r] = f2h(Ci[r] + bi);
        }
        *(us4v*)&vtr[tix] = pr;
        *(us4v*)&vti[tix] = pi;
    };
    auto gtile = [&](const Afrag& A, int nt) {
        f4 Cr, Ci;
        ctile(A, gwr, gwi, nt * 16, Cr, Ci);
        int c = nt * 16 + m16;
        float br = gbr[c], bi = gbi[c];
        #pragma unroll
        for (int r = 0; r < 4; ++r) {
            int g = rowbase + quad * 4 + r;
            out_gr[g * 64 + c] = Cr[r] + br;
            out_gi[g * 64 + c] = Ci[r] + bi;
        }
    };

    if (wv == 0) {
        Afrag Aq = loadA(q_r, q_i);
        qtile(Aq, 0); qtile(Aq, 1); qtile(Aq, 2); qtile(Aq, 3); qtile(Aq, 4);
    } else if (wv == 1) {
        Afrag Aq = loadA(q_r, q_i);
        qtile(Aq, 5); qtile(Aq, 6); qtile(Aq, 7);
        gtile(Aq, 0); gtile(Aq, 1);
    } else if (wv == 2) {
        Afrag Ak = loadA(k_r, k_i);
        ktile(Ak, 0); ktile(Ak, 1); ktile(Ak, 2); ktile(Ak, 3);
        Afrag Aq = loadA(q_r, q_i);
        gtile(Aq, 2);
    } else {
        Afrag Av = loadA(v_r, v_i);
        vtile(Av, 0); vtile(Av, 1); vtile(Av, 2); vtile(Av, 3);
        Afrag Aq = loadA(q_r, q_i);
        gtile(Aq, 3);
    }
}

// ---------------------------------------------------------------------------
// Kernel 2: MFMA flash attention.
//   Round-12: back to LDS staging (R3's global-direct B-frags were
//   uncoalesced: 16 cache lines per load -> latency-bound, 2.4x slower).
//   New structure: 32 q-rows/wave (2 row-tiles), branches MERGED in one
//   block (waves 0-1 branch1, waves 2-3 branch2) -> K/V staged ONCE per
//   block and each staged tile feeds 2x the MFMA work per ds_read.
//   DS-read volume per CU per kt: 272 -> 144 b128. 1 block/CU, ILP from
//   dual row-tiles replaces TLP. T2 swizzle, T13 defer-max, T14 staging,
//   f32 L-partials, raw sqrt, setprio retained.
// ---------------------------------------------------------------------------
__global__ __launch_bounds__(256, 1) void attn_kernel(
    const u16* __restrict__ q1r, const u16* __restrict__ q1i,
    const u16* __restrict__ q2r, const u16* __restrict__ q2i,
    const u16* __restrict__ kpr, const u16* __restrict__ kpi,
    const u16* __restrict__ vtr, const u16* __restrict__ vti,
    u16* __restrict__ o1r, u16* __restrict__ o1i,
    u16* __restrict__ o2r, u16* __restrict__ o2i)
{
    __shared__ __align__(16) u16 Kr[64 * 64], Ki[64 * 64];
    __shared__ __align__(16) u16 Vr[64 * 64], Vi[64 * 64];
    __shared__ __align__(16) u16 Pb[128 * 64];

    const int t  = threadIdx.x;
    const int qt = blockIdx.x;
    const int h  = blockIdx.z;

    const int wq   = t >> 6;     // wave 0..3
    const int br   = wq >> 1;    // branch
    const int rh   = wq & 1;     // row-half within the 64-row q tile
    const int l    = t & 63;
    const int quad = l >> 4;
    const int m    = l & 15;

    const u16* Qsr = br ? q2r : q1r;
    const u16* Qsi = br ? q2i : q1i;
    const int hbase = h * SQ * 64;
    const int qbase = hbase + qt * 64 * 64;
    const int vbase = h * 64 * SQ;

    // ---- Q fragments: 2 row-tiles of 16 rows each (rows rh*32 + rs*16 + m) ----
    h8 Qr0[2], Qr1[2], Qi0[2], Qi1[2], nQr0[2], nQr1[2];
    #pragma unroll
    for (int rs = 0; rs < 2; ++rs) {
        const u16* qrr = Qsr + qbase + (rh * 32 + rs * 16 + m) * 64;
        const u16* qri = Qsi + qbase + (rh * 32 + rs * 16 + m) * 64;
        Qr0[rs] = *(const h8*)(qrr + quad * 8);
        Qr1[rs] = *(const h8*)(qrr + 32 + quad * 8);
        Qi0[rs] = *(const h8*)(qri + quad * 8);
        Qi1[rs] = *(const h8*)(qri + 32 + quad * 8);
        nQr0[rs] = neg_h8(Qr0[rs]);
        nQr1[rs] = neg_h8(Qr1[rs]);
    }

    // ---- T14 staging: global -> reg (issued one tile ahead) -> LDS ----
    const int sr0 = t >> 3;           // rows 0..31 (+32 for second chunk)
    const int sc  = t & 7;            // 8-u16 chunk index
    us8 rK0, rK1, rC0, rC1, rV0, rV1, rW0, rW1;

    auto issue = [&](int kt) {
        const int kb = hbase + kt * 4096;
        const int vb = vbase + kt * 64;
        const int sc8 = sc * 8;
        rK0 = *(const us8*)(kpr + kb + sr0 * 64 + sc8);
        rK1 = *(const us8*)(kpr + kb + (sr0 + 32) * 64 + sc8);
        rC0 = *(const us8*)(kpi + kb + sr0 * 64 + sc8);
        rC1 = *(const us8*)(kpi + kb + (sr0 + 32) * 64 + sc8);
        rV0 = *(const us8*)(vtr + vb + sr0 * SQ + sc8);
        rV1 = *(const us8*)(vtr + vb + (sr0 + 32) * SQ + sc8);
        rW0 = *(const us8*)(vti + vb + sr0 * SQ + sc8);
        rW1 = *(const us8*)(vti + vb + (sr0 + 32) * SQ + sc8);
    };
    auto commit = [&]() {
        const int o0 = swz8(sr0, sc);        // (sr0+32)&7 == sr0&7
        const int o1 = swz8(sr0 + 32, sc);
        *(us8*)&Kr[o0] = rK0;  *(us8*)&Kr[o1] = rK1;
        *(us8*)&Ki[o0] = rC0;  *(us8*)&Ki[o1] = rC1;
        *(us8*)&Vr[o0] = rV0;  *(us8*)&Vr[o1] = rV1;
        *(us8*)&Vi[o0] = rW0;  *(us8*)&Vi[o1] = rW1;
    };

    float mreg[2][4], Lp[2][4];
    #pragma unroll
    for (int rs = 0; rs < 2; ++rs)
        #pragma unroll
        for (int r = 0; r < 4; ++r) { mreg[rs][r] = -1e30f; Lp[rs][r] = 0.f; }
    f4 Ovr[2][4], Ovi[2][4];
    #pragma unroll
    for (int rs = 0; rs < 2; ++rs)
        #pragma unroll
        for (int d = 0; d < 4; ++d) { Ovr[rs][d] = (f4)0.f; Ovi[rs][d] = (f4)0.f; }

    issue(0);

    for (int kt = 0; kt < 32; ++kt) {
        __syncthreads();                 // all waves done reading prev tile
        commit();                        // regs (kt) -> LDS
        if (kt < 31) issue(kt + 1);      // loads in flight under compute
        __syncthreads();                 // tile kt ready

        // ---- QK^T (complex magnitude scores): K-frags shared by both row-tiles ----
        float sv[2][4][4];
        #pragma unroll
        for (int nt = 0; nt < 4; ++nt) {
            const int kr = nt * 16 + m;
            h8 k0 = *(const h8*)&Kr[swz8(kr, quad)];
            h8 k1 = *(const h8*)&Kr[swz8(kr, quad + 4)];
            h8 c0 = *(const h8*)&Ki[swz8(kr, quad)];
            h8 c1 = *(const h8*)&Ki[swz8(kr, quad + 4)];
            __builtin_amdgcn_s_setprio(1);
            #pragma unroll
            for (int rs = 0; rs < 2; ++rs) {
                f4 ar = (f4)0.f, ai = (f4)0.f;
                ar = MFMA_F16(Qr0[rs], k0, ar, 0, 0, 0);
                ar = MFMA_F16(Qr1[rs], k1, ar, 0, 0, 0);
                ar = MFMA_F16(Qi0[rs], c0, ar, 0, 0, 0);
                ar = MFMA_F16(Qi1[rs], c1, ar, 0, 0, 0);
                ai = MFMA_F16(Qi0[rs], k0, ai, 0, 0, 0);
                ai = MFMA_F16(Qi1[rs], k1, ai, 0, 0, 0);
                ai = MFMA_F16(nQr0[rs], c0, ai, 0, 0, 0);
                ai = MFMA_F16(nQr1[rs], c1, ai, 0, 0, 0);
                #pragma unroll
                for (int r = 0; r < 4; ++r)
                    sv[rs][nt][r] =
                        __builtin_amdgcn_sqrtf(ar[r] * ar[r] + ai[r] * ai[r] + 1e-8f) * 0.125f;
            }
            __builtin_amdgcn_s_setprio(0);
        }

        // ---- exact per-row tile max (16-lane reduce) + T13 defer-max ----
        float rv[2][4];
        bool need = false;
        #pragma unroll
        for (int rs = 0; rs < 2; ++rs)
            #pragma unroll
            for (int r = 0; r < 4; ++r) {
                float x = fmaxf(fmaxf(sv[rs][0][r], sv[rs][1][r]),
                                fmaxf(sv[rs][2][r], sv[rs][3][r]));
                x = fmaxf(x, __shfl_xor(x, 1));
                x = fmaxf(x, __shfl_xor(x, 2));
                x = fmaxf(x, __shfl_xor(x, 4));
                x = fmaxf(x, __shfl_xor(x, 8));
                rv[rs][r] = x;
                need |= (x > mreg[rs][r] + 8.f);
            }
        if (__any(need)) {
            #pragma unroll
            for (int rs = 0; rs < 2; ++rs)
                #pragma unroll
                for (int r = 0; r < 4; ++r) {
                    float mn = fmaxf(mreg[rs][r], rv[rs][r]);
                    float al = __expf(mreg[rs][r] - mn);
                    mreg[rs][r] = mn;
                    Lp[rs][r] *= al;
                    #pragma unroll
                    for (int dt = 0; dt < 4; ++dt) {
                        Ovr[rs][dt][r] *= al; Ovi[rs][dt][r] *= al;
                    }
                }
        }

        // ---- P = exp(s - m)  (f32 row-sum partials; f16 to LDS for MFMA) ----
        #pragma unroll
        for (int rs = 0; rs < 2; ++rs)
            #pragma unroll
            for (int r = 0; r < 4; ++r) {
                const int prow = wq * 32 + rs * 16 + quad * 4 + r;
                #pragma unroll
                for (int nt = 0; nt < 4; ++nt) {
                    float p = __expf(sv[rs][nt][r] - mreg[rs][r]);
                    Lp[rs][r] += p;
                    const int col = nt * 16 + m;
                    Pb[swz8(prow, col >> 3) + (col & 7)] = f2h(p);
                }
            }

        h8 pa0[2], pa1[2];
        #pragma unroll
        for (int rs = 0; rs < 2; ++rs) {
            const int qrow = wq * 32 + rs * 16 + m;
            pa0[rs] = *(const h8*)&Pb[swz8(qrow, quad)];
            pa1[rs] = *(const h8*)&Pb[swz8(qrow, quad + 4)];
        }

        // ---- PV: V-frags shared by both row-tiles ----
        #pragma unroll
        for (int dt = 0; dt < 4; ++dt) {
            const int vr_ = dt * 16 + m;
            h8 b0 = *(const h8*)&Vr[swz8(vr_, quad)];
            h8 b1 = *(const h8*)&Vr[swz8(vr_, quad + 4)];
            h8 d0 = *(const h8*)&Vi[swz8(vr_, quad)];
            h8 d1 = *(const h8*)&Vi[swz8(vr_, quad + 4)];
            __builtin_amdgcn_s_setprio(1);
            #pragma unroll
            for (int rs = 0; rs < 2; ++rs) {
                Ovr[rs][dt] = MFMA_F16(pa0[rs], b0, Ovr[rs][dt], 0, 0, 0);
                Ovr[rs][dt] = MFMA_F16(pa1[rs], b1, Ovr[rs][dt], 0, 0, 0);
                Ovi[rs][dt] = MFMA_F16(pa0[rs], d0, Ovi[rs][dt], 0, 0, 0);
                Ovi[rs][dt] = MFMA_F16(pa1[rs], d1, Ovi[rs][dt], 0, 0, 0);
            }
            __builtin_amdgcn_s_setprio(0);
        }
    }

    {
        u16* Dr = br ? o2r : o1r;
        u16* Di = br ? o2i : o1i;
        #pragma unroll
        for (int rs = 0; rs < 2; ++rs) {
            float inv[4];
            #pragma unroll
            for (int r = 0; r < 4; ++r) {
                float x = Lp[rs][r];
                x += __shfl_xor(x, 1);
                x += __shfl_xor(x, 2);
                x += __shfl_xor(x, 4);
                x += __shfl_xor(x, 8);
                inv[r] = 1.f / x;
            }
            #pragma unroll
            for (int dt = 0; dt < 4; ++dt) {
                #pragma unroll
                for (int r = 0; r < 4; ++r) {
                    int q = rh * 32 + rs * 16 + quad * 4 + r;
                    Dr[qbase + q * 64 + dt * 16 + m] = f2h(Ovr[rs][dt][r] * inv[r]);
                    Di[qbase + q * 64 + dt * 16 + m] = f2h(Ovi[rs][dt][r] * inv[r]);
                }
            }
        }
    }
}

// ---------------------------------------------------------------------------
// Kernel 3: MFMA epilogue (unchanged).
// ---------------------------------------------------------------------------
__global__ __launch_bounds__(256) void epi_kernel(
    const u16* __restrict__ o1r, const u16* __restrict__ o1i,
    const u16* __restrict__ o2r, const u16* __restrict__ o2i,
    const float* __restrict__ out_gr, const float* __restrict__ out_gi,
    const float* __restrict__ subw,
    const float* __restrict__ owr, const float* __restrict__ owi,
    const float* __restrict__ obr, const float* __restrict__ obi,
    float* __restrict__ out_r, float* __restrict__ out_i)
{
    __shared__ __align__(16) u16 L1r[16][64], L1i[16][64];
    __shared__ __align__(16) u16 L2r[16][64], L2i[16][64];
    __shared__ __align__(16) u16 Xr[16][PIT], Xi[16][PIT];

    const int t = threadIdx.x;
    const int rowbase = blockIdx.x * 16;

    // ---- stage o1/o2 (coalesced 8B loads) ----
    {
        int r = t >> 4, c4 = (t & 15) * 4;
        size_t gi = (size_t)(rowbase + r) * 64 + c4;
        *(us4v*)&L1r[r][c4] = *(const us4v*)(o1r + gi);
        *(us4v*)&L1i[r][c4] = *(const us4v*)(o1i + gi);
        *(us4v*)&L2r[r][c4] = *(const us4v*)(o2r + gi);
        *(us4v*)&L2i[r][c4] = *(const us4v*)(o2i + gi);
    }
    __syncthreads();

    // ---- RMS (joint over o1,o2 = all 128 interleaved cols) + x ----
    {
        int r = t >> 4, c4 = (t & 15) * 4;
        float ss = 0.f;
        #pragma unroll
        for (int j = 0; j < 4; ++j) {
            float a = h2f(L1r[r][c4 + j]), b = h2f(L1i[r][c4 + j]);
            float c = h2f(L2r[r][c4 + j]), d = h2f(L2i[r][c4 + j]);
            ss += a * a + b * b + c * c + d * d;
        }
        ss += __shfl_xor(ss, 1);
        ss += __shfl_xor(ss, 2);
        ss += __shfl_xor(ss, 4);
        ss += __shfl_xor(ss, 8);
        float inv = 1.f / sqrtf(ss * (1.f / 128.f) + 1e-5f);

        float4 g_r = *(const float4*)(out_gr + (size_t)(rowbase + r) * 64 + c4);
        float4 g_i = *(const float4*)(out_gi + (size_t)(rowbase + r) * 64 + c4);
        const float* grv = (const float*)&g_r;
        const float* giv = (const float*)&g_i;

        us4v xrp, xip;
        #pragma unroll
        for (int j = 0; j < 4; ++j) {
            int c = c4 + j;
            int s = c >> 1;
            float cr_ = (c & 1) ? h2f(L2r[r][s]) : h2f(L1r[r][s]);
            float ci_ = (c & 1) ? h2f(L2i[r][s]) : h2f(L1i[r][s]);
            float sw = subw[c];
            float ar_ = cr_ * inv * sw;
            float ai_ = ci_ * inv * sw;
            xrp[j] = f2h(grv[j] * ar_ - giv[j] * ai_);
            xip[j] = f2h(grv[j] * ai_ + giv[j] * ar_);
        }
        *(us4v*)&Xr[r][c4] = xrp;
        *(us4v*)&Xi[r][c4] = xip;
    }
    __syncthreads();

    // ---- out-projection: wave w = n-tile w ----
    const int wv = t >> 6, l = t & 63;
    const int quad = l >> 4, m16 = l & 15;
    const int c0 = quad * 8;

    h8 Ar0 = *(const h8*)&Xr[m16][c0];
    h8 Ar1 = *(const h8*)&Xr[m16][32 + c0];
    h8 Ai0 = *(const h8*)&Xi[m16][c0];
    h8 Ai1 = *(const h8*)&Xi[m16][32 + c0];
    h8 nAi0 = neg_h8(Ai0), nAi1 = neg_h8(Ai1);

    const int c = wv * 16 + m16;
    const float* wrp = owr + c * 64;
    const float* wip = owi + c * 64;
    h8 Br0 = pack8h(wrp + c0), Br1 = pack8h(wrp + 32 + c0);
    h8 Bi0 = pack8h(wip + c0), Bi1 = pack8h(wip + 32 + c0);

    f4 Cr = (f4)0.f, Ci = (f4)0.f;
    Cr = MFMA_F16(Ar0,  Br0, Cr, 0, 0, 0);
    Cr = MFMA_F16(Ar1,  Br1, Cr, 0, 0, 0);
    Cr = MFMA_F16(nAi0, Bi0, Cr, 0, 0, 0);
    Cr = MFMA_F16(nAi1, Bi1, Cr, 0, 0, 0);
    Ci = MFMA_F16(Ar0,  Bi0, Ci, 0, 0, 0);
    Ci = MFMA_F16(Ar1,  Bi1, Ci, 0, 0, 0);
    Ci = MFMA_F16(Ai0,  Br0, Ci, 0, 0, 0);
    Ci = MFMA_F16(Ai1,  Br1, Ci, 0, 0, 0);

    float br_ = obr[c], bi_ = obi[c];
    #pragma unroll
    for (int r = 0; r < 4; ++r) {
        size_t g = (size_t)(rowbase + quad * 4 + r) * 64 + c;
        out_r[g] = Cr[r] + br_;
        out_i[g] = Ci[r] + bi_;
    }
}

// ---------------------------------------------------------------------------
extern "C" void kernel_launch(void* const* d_in, const int* in_sizes, int n_in,
                              void* d_out, int out_size, void* d_ws, size_t ws_size,
                              hipStream_t stream)
{
    (void)in_sizes; (void)n_in; (void)out_size; (void)ws_size;

    float* out    = (float*)d_out;
    float* out_r  = out;
    float* out_i  = out + (size_t)NTOT;
    float* out_gr = out + 2 * (size_t)NTOT;
    float* out_gi = out + 3 * (size_t)NTOT;

    // workspace layout (f16 only), 24 MB total
    char* w = (char*)d_ws;
    const size_t N = (size_t)NTOT;
    u16* q1r = (u16*)w; w += N * 2;
    u16* q1i = (u16*)w; w += N * 2;
    u16* q2r = (u16*)w; w += N * 2;
    u16* q2i = (u16*)w; w += N * 2;
    u16* kpr = (u16*)w; w += N * 2;
    u16* kpi = (u16*)w; w += N * 2;
    u16* vtr = (u16*)w; w += N * 2;   // [h][d][s]
    u16* vti = (u16*)w; w += N * 2;   // [h][d][s]
    u16* o1r = (u16*)w; w += N * 2;
    u16* o1i = (u16*)w; w += N * 2;
    u16* o2r = (u16*)w; w += N * 2;
    u16* o2i = (u16*)w; w += N * 2;

    proj_kernel<<<dim3(1024), dim3(256), 0, stream>>>(
        (const float*)d_in[0], (const float*)d_in[1],
        (const float*)d_in[2], (const float*)d_in[3],
        (const float*)d_in[4], (const float*)d_in[5],
        (const float*)d_in[6], (const float*)d_in[7],
        (const float*)d_in[8], (const float*)d_in[9],
        (const float*)d_in[10], (const float*)d_in[11],
        (const float*)d_in[12], (const float*)d_in[13],
        (const float*)d_in[14], (const float*)d_in[15],
        (const float*)d_in[16], (const float*)d_in[17],
        (const float*)d_in[18], (const float*)d_in[19],
        (const float*)d_in[20], (const float*)d_in[21],
        (const float*)d_in[22], (const float*)d_in[23],
        (const float*)d_in[24], (const float*)d_in[25],
        q1r, q1i, q2r, q2i, kpr, kpi, vtr, vti, out_gr, out_gi);

    attn_kernel<<<dim3(SQ / 64, 1, NH), dim3(256), 0, stream>>>(
        q1r, q1i, q2r, q2i, kpr, kpi, vtr, vti, o1r, o1i, o2r, o2i);

    epi_kernel<<<dim3(1024), dim3(256), 0, stream>>>(
        o1r, o1i, o2r, o2i, out_gr, out_gi,
        (const float*)d_in[34], (const float*)d_in[26], (const float*)d_in[27],
        (const float*)d_in[28], (const float*)d_in[29],
        out_r, out_i);
}

// Round 5
// 247.794 us; speedup vs baseline: 1.6421x; 1.1870x over previous
//
#include <hip/hip_runtime.h>
#include <hip/hip_bf16.h>

#define NH 8
#define SQ 2048
#define HD 64
#define NTOT (NH * SQ * HD)   // 1048576
#define PIT 72                 // LDS row pitch in u16 (epi kernel only)

typedef unsigned short u16;
typedef unsigned int u32;
typedef __attribute__((ext_vector_type(8))) unsigned short us8;
typedef __attribute__((ext_vector_type(4))) unsigned short us4v;
typedef __attribute__((ext_vector_type(8))) _Float16 h8;   // MFMA f16 A/B fragment
typedef __attribute__((ext_vector_type(4))) float f4;      // MFMA C/D fragment
typedef __attribute__((ext_vector_type(4))) u32 u4;

#define MFMA_F16 __builtin_amdgcn_mfma_f32_16x16x32_f16

__device__ __forceinline__ u16 f2h(float f) {
    union { _Float16 h; u16 u; } c; c.h = (_Float16)f; return c.u;
}
__device__ __forceinline__ float h2f(u16 u) {
    union { _Float16 h; u16 u; } c; c.u = u; return (float)c.h;
}
__device__ __forceinline__ h8 neg_h8(h8 a) {
    union { h8 h; u4 u; } c; c.h = a;
    c.u ^= 0x80008000u;
    return c.h;
}
// 8 contiguous f32 -> f16x8 fragment (two float4 loads, hw cvt)
__device__ __forceinline__ h8 pack8h(const float* p) {
    float4 a = ((const float4*)p)[0];
    float4 b = ((const float4*)p)[1];
    h8 r;
    r[0] = (_Float16)a.x; r[1] = (_Float16)a.y; r[2] = (_Float16)a.z; r[3] = (_Float16)a.w;
    r[4] = (_Float16)b.x; r[5] = (_Float16)b.y; r[6] = (_Float16)b.z; r[7] = (_Float16)b.w;
    return r;
}

// T2 swizzle: pitch 64 u16 (128B rows), 16B-chunk index XOR'd with row&7.
__device__ __forceinline__ int swz8(int row, int chunk) {   // u16 offset of 8-u16 chunk
    return row * 64 + ((chunk ^ (row & 7)) << 3);
}

struct Afrag { h8 r0, r1, i0, i1, ni0, ni1; };

// ---------------------------------------------------------------------------
// Kernel 1: MFMA complex projections (unchanged).
// ---------------------------------------------------------------------------
__global__ __launch_bounds__(256) void proj_kernel(
    const float* __restrict__ q_r, const float* __restrict__ q_i,
    const float* __restrict__ k_r, const float* __restrict__ k_i,
    const float* __restrict__ v_r, const float* __restrict__ v_i,
    const float* __restrict__ pe_q_r, const float* __restrict__ pe_q_i,
    const float* __restrict__ pe_k_r, const float* __restrict__ pe_k_i,
    const float* __restrict__ qwr, const float* __restrict__ qwi,
    const float* __restrict__ qbr, const float* __restrict__ qbi,
    const float* __restrict__ kwr, const float* __restrict__ kwi,
    const float* __restrict__ kbr, const float* __restrict__ kbi,
    const float* __restrict__ vwr, const float* __restrict__ vwi,
    const float* __restrict__ vbr, const float* __restrict__ vbi,
    const float* __restrict__ gwr, const float* __restrict__ gwi,
    const float* __restrict__ gbr, const float* __restrict__ gbi,
    u16* __restrict__ q1r, u16* __restrict__ q1i,
    u16* __restrict__ q2r, u16* __restrict__ q2i,
    u16* __restrict__ kpr, u16* __restrict__ kpi,
    u16* __restrict__ vtr, u16* __restrict__ vti,
    float* __restrict__ out_gr, float* __restrict__ out_gi)
{
    const int t = threadIdx.x;
    const int wv = t >> 6, l = t & 63;
    const int quad = l >> 4, m16 = l & 15;
    const int rowbase = blockIdx.x * 16;
    const int arow = rowbase + m16;
    const int h = rowbase >> 11;
    const int c0 = quad * 8;

    auto loadA = [&](const float* pr, const float* pi) {
        Afrag a;
        const float* rp = pr + arow * 64;
        const float* ip = pi + arow * 64;
        a.r0 = pack8h(rp + c0);      a.r1 = pack8h(rp + 32 + c0);
        a.i0 = pack8h(ip + c0);      a.i1 = pack8h(ip + 32 + c0);
        a.ni0 = neg_h8(a.i0);        a.ni1 = neg_h8(a.i1);
        return a;
    };

    auto ctile = [&](const Afrag& A, const float* wr, const float* wi, int cb,
                     f4& Cr, f4& Ci) {
        const float* wrp = wr + (cb + m16) * 64;
        const float* wip = wi + (cb + m16) * 64;
        h8 Br0 = pack8h(wrp + c0), Br1 = pack8h(wrp + 32 + c0);
        h8 Bi0 = pack8h(wip + c0), Bi1 = pack8h(wip + 32 + c0);
        Cr = (f4)0.f; Ci = (f4)0.f;
        Cr = MFMA_F16(A.r0,  Br0, Cr, 0, 0, 0);
        Cr = MFMA_F16(A.r1,  Br1, Cr, 0, 0, 0);
        Cr = MFMA_F16(A.ni0, Bi0, Cr, 0, 0, 0);
        Cr = MFMA_F16(A.ni1, Bi1, Cr, 0, 0, 0);
        Ci = MFMA_F16(A.r0,  Bi0, Ci, 0, 0, 0);
        Ci = MFMA_F16(A.r1,  Bi1, Ci, 0, 0, 0);
        Ci = MFMA_F16(A.i0,  Br0, Ci, 0, 0, 0);
        Ci = MFMA_F16(A.i1,  Br1, Ci, 0, 0, 0);
    };

    auto qtile = [&](const Afrag& A, int nt) {
        f4 Cr, Ci;
        ctile(A, qwr, qwi, nt * 16, Cr, Ci);
        int c = nt * 16 + m16;
        float br = qbr[c], bi = qbi[c];
        int dd = c >> 1, pc = c & 63;
        u16* dR = (c & 1) ? q2r : q1r;
        u16* dI = (c & 1) ? q2i : q1i;
        #pragma unroll
        for (int r = 0; r < 4; ++r) {
            int g = rowbase + quad * 4 + r;
            dR[g * 64 + dd] = f2h(Cr[r] + br + pe_q_r[g * 64 + pc]);
            dI[g * 64 + dd] = f2h(Ci[r] + bi + pe_q_i[g * 64 + pc]);
        }
    };
    auto ktile = [&](const Afrag& A, int nt) {
        f4 Cr, Ci;
        ctile(A, kwr, kwi, nt * 16, Cr, Ci);
        int c = nt * 16 + m16;
        float br = kbr[c], bi = kbi[c];
        #pragma unroll
        for (int r = 0; r < 4; ++r) {
            int g = rowbase + quad * 4 + r;
            kpr[g * 64 + c] = f2h(Cr[r] + br + pe_k_r[g * 64 + c]);
            kpi[g * 64 + c] = f2h(Ci[r] + bi + pe_k_i[g * 64 + c]);
        }
    };
    auto vtile = [&](const Afrag& A, int nt) {
        f4 Cr, Ci;
        ctile(A, vwr, vwi, nt * 16, Cr, Ci);
        int c = nt * 16 + m16;
        float br = vbr[c], bi = vbi[c];
        int s0 = (rowbase & 2047) + quad * 4;
        size_t tix = (size_t)(h * 64 + c) * 2048 + s0;
        us4v pr, pi;
        #pragma unroll
        for (int r = 0; r < 4; ++r) {
            pr[r] = f2h(Cr[r] + br);
            pi[r] = f2h(Ci[r] + bi);
        }
        *(us4v*)&vtr[tix] = pr;
        *(us4v*)&vti[tix] = pi;
    };
    auto gtile = [&](const Afrag& A, int nt) {
        f4 Cr, Ci;
        ctile(A, gwr, gwi, nt * 16, Cr, Ci);
        int c = nt * 16 + m16;
        float br = gbr[c], bi = gbi[c];
        #pragma unroll
        for (int r = 0; r < 4; ++r) {
            int g = rowbase + quad * 4 + r;
            out_gr[g * 64 + c] = Cr[r] + br;
            out_gi[g * 64 + c] = Ci[r] + bi;
        }
    };

    if (wv == 0) {
        Afrag Aq = loadA(q_r, q_i);
        qtile(Aq, 0); qtile(Aq, 1); qtile(Aq, 2); qtile(Aq, 3); qtile(Aq, 4);
    } else if (wv == 1) {
        Afrag Aq = loadA(q_r, q_i);
        qtile(Aq, 5); qtile(Aq, 6); qtile(Aq, 7);
        gtile(Aq, 0); gtile(Aq, 1);
    } else if (wv == 2) {
        Afrag Ak = loadA(k_r, k_i);
        ktile(Ak, 0); ktile(Ak, 1); ktile(Ak, 2); ktile(Ak, 3);
        Afrag Aq = loadA(q_r, q_i);
        gtile(Aq, 2);
    } else {
        Afrag Av = loadA(v_r, v_i);
        vtile(Av, 0); vtile(Av, 1); vtile(Av, 2); vtile(Av, 3);
        Afrag Aq = loadA(q_r, q_i);
        gtile(Aq, 3);
    }
}

// ---------------------------------------------------------------------------
// Kernel 2: MFMA flash attention.
//   Round-13: R2 structure (8 waves/CU, 16 q-rows/wave, verified softmax)
//   with two mechanical cuts:
//   - branches merged into ONE 512-thread block (waves 0-3 br1, 4-7 br2):
//     K/V staged once per CU per kt (commit volume halved).
//   - double-buffered K/V + ONE barrier per kt: commit(kt+1) -> issue(kt+2)
//     -> compute(kt) -> barrier. Commit's vmcnt wait is covered by a full
//     iteration; one barrier drain per kt eliminated.
//   LDS = 64KB K/V dbuf + 16KB Pb = 80KB, 1 block/CU.
// ---------------------------------------------------------------------------
__global__ __launch_bounds__(512, 2) void attn_kernel(
    const u16* __restrict__ q1r, const u16* __restrict__ q1i,
    const u16* __restrict__ q2r, const u16* __restrict__ q2i,
    const u16* __restrict__ kpr, const u16* __restrict__ kpi,
    const u16* __restrict__ vtr, const u16* __restrict__ vti,
    u16* __restrict__ o1r, u16* __restrict__ o1i,
    u16* __restrict__ o2r, u16* __restrict__ o2i)
{
    __shared__ __align__(16) u16 Kr[2][64 * 64], Ki[2][64 * 64];
    __shared__ __align__(16) u16 Vr[2][64 * 64], Vi[2][64 * 64];
    __shared__ __align__(16) u16 Pb[128 * 64];

    const int t  = threadIdx.x;      // 0..511
    const int qt = blockIdx.x;
    const int h  = blockIdx.z;

    const int wq   = t >> 6;         // wave 0..7
    const int br   = wq >> 2;        // branch
    const int wr   = wq & 3;         // 16-row block within the 64-row q tile
    const int l    = t & 63;
    const int quad = l >> 4;
    const int m    = l & 15;

    const u16* Qsr = br ? q2r : q1r;
    const u16* Qsi = br ? q2i : q1i;
    const int hbase = h * SQ * 64;
    const int qbase = hbase + qt * 64 * 64;
    const int vbase = h * 64 * SQ;

    const u16* qrr = Qsr + qbase + (wr * 16 + m) * 64;
    const u16* qri = Qsi + qbase + (wr * 16 + m) * 64;
    h8 Qr0 = *(const h8*)(qrr + quad * 8);
    h8 Qr1 = *(const h8*)(qrr + 32 + quad * 8);
    h8 Qi0 = *(const h8*)(qri + quad * 8);
    h8 Qi1 = *(const h8*)(qri + 32 + quad * 8);
    h8 nQr0 = neg_h8(Qr0);
    h8 nQr1 = neg_h8(Qr1);

    // ---- staging: 512 threads cover one 64x64 u16 tile per array ----
    const int sr0 = t >> 3;           // row 0..63
    const int sc  = t & 7;            // 8-u16 chunk
    us8 rK, rC, rV, rW;

    auto issue = [&](int kt) {
        const int kb = hbase + kt * 4096;
        const int vb = vbase + kt * 64;
        const int sc8 = sc * 8;
        rK = *(const us8*)(kpr + kb + sr0 * 64 + sc8);
        rC = *(const us8*)(kpi + kb + sr0 * 64 + sc8);
        rV = *(const us8*)(vtr + vb + sr0 * SQ + sc8);
        rW = *(const us8*)(vti + vb + sr0 * SQ + sc8);
    };
    auto commit = [&](int b) {
        const int o = swz8(sr0, sc);
        *(us8*)&Kr[b][o] = rK;
        *(us8*)&Ki[b][o] = rC;
        *(us8*)&Vr[b][o] = rV;
        *(us8*)&Vi[b][o] = rW;
    };

    float mreg[4], Lp[4];
    #pragma unroll
    for (int r = 0; r < 4; ++r) { mreg[r] = -1e30f; Lp[r] = 0.f; }
    f4 Ovr[4], Ovi[4];
    #pragma unroll
    for (int d = 0; d < 4; ++d) { Ovr[d] = (f4)0.f; Ovi[d] = (f4)0.f; }

    // prologue: tile0 -> buf0; loads for tile1 in flight
    issue(0);
    commit(0);          // compiler inserts vmcnt wait
    issue(1);
    __syncthreads();

    for (int kt = 0; kt < 32; ++kt) {
        const int cur = kt & 1;
        if (kt < 31) commit(cur ^ 1);    // tile kt+1 regs -> other buffer
        if (kt < 30) issue(kt + 2);      // loads in flight across this iter

        // ---- QK^T (complex magnitude scores) ----
        float sv[4][4];
        #pragma unroll
        for (int nt = 0; nt < 4; ++nt) {
            const int kr = nt * 16 + m;
            h8 k0 = *(const h8*)&Kr[cur][swz8(kr, quad)];
            h8 k1 = *(const h8*)&Kr[cur][swz8(kr, quad + 4)];
            h8 c0 = *(const h8*)&Ki[cur][swz8(kr, quad)];
            h8 c1 = *(const h8*)&Ki[cur][swz8(kr, quad + 4)];
            f4 ar = (f4)0.f, ai = (f4)0.f;
            __builtin_amdgcn_s_setprio(1);
            ar = MFMA_F16(Qr0, k0, ar, 0, 0, 0);
            ar = MFMA_F16(Qr1, k1, ar, 0, 0, 0);
            ar = MFMA_F16(Qi0, c0, ar, 0, 0, 0);
            ar = MFMA_F16(Qi1, c1, ar, 0, 0, 0);
            ai = MFMA_F16(Qi0, k0, ai, 0, 0, 0);
            ai = MFMA_F16(Qi1, k1, ai, 0, 0, 0);
            ai = MFMA_F16(nQr0, c0, ai, 0, 0, 0);
            ai = MFMA_F16(nQr1, c1, ai, 0, 0, 0);
            __builtin_amdgcn_s_setprio(0);
            #pragma unroll
            for (int r = 0; r < 4; ++r)
                sv[nt][r] = __builtin_amdgcn_sqrtf(ar[r] * ar[r] + ai[r] * ai[r] + 1e-8f) * 0.125f;
        }

        // ---- exact per-row tile max (16-lane reduce) ----
        float rv[4];
        #pragma unroll
        for (int r = 0; r < 4; ++r) {
            float x = fmaxf(fmaxf(sv[0][r], sv[1][r]), fmaxf(sv[2][r], sv[3][r]));
            x = fmaxf(x, __shfl_xor(x, 1));
            x = fmaxf(x, __shfl_xor(x, 2));
            x = fmaxf(x, __shfl_xor(x, 4));
            x = fmaxf(x, __shfl_xor(x, 8));
            rv[r] = x;
        }

        // ---- T13 defer-max: rescale only when a row grows past slack ----
        bool need = (rv[0] > mreg[0] + 8.f) | (rv[1] > mreg[1] + 8.f) |
                    (rv[2] > mreg[2] + 8.f) | (rv[3] > mreg[3] + 8.f);
        if (__any(need)) {
            #pragma unroll
            for (int r = 0; r < 4; ++r) {
                float mn = fmaxf(mreg[r], rv[r]);
                float al = __expf(mreg[r] - mn);
                mreg[r] = mn;
                Lp[r] *= al;
                #pragma unroll
                for (int dtr = 0; dtr < 4; ++dtr) { Ovr[dtr][r] *= al; Ovi[dtr][r] *= al; }
            }
        }

        // ---- P = exp(s - m)  (f32 row-sum partials; f16 to LDS for MFMA) ----
        #pragma unroll
        for (int r = 0; r < 4; ++r) {
            const int prow = wq * 16 + quad * 4 + r;
            #pragma unroll
            for (int nt = 0; nt < 4; ++nt) {
                float p = __expf(sv[nt][r] - mreg[r]);
                Lp[r] += p;
                const int col = nt * 16 + m;
                Pb[swz8(prow, col >> 3) + (col & 7)] = f2h(p);
            }
        }

        const int qrow = wq * 16 + m;
        h8 pa0 = *(const h8*)&Pb[swz8(qrow, quad)];
        h8 pa1 = *(const h8*)&Pb[swz8(qrow, quad + 4)];

        // ---- PV ----
        #pragma unroll
        for (int dt = 0; dt < 4; ++dt) {
            const int vr_ = dt * 16 + m;
            h8 b0 = *(const h8*)&Vr[cur][swz8(vr_, quad)];
            h8 b1 = *(const h8*)&Vr[cur][swz8(vr_, quad + 4)];
            h8 d0 = *(const h8*)&Vi[cur][swz8(vr_, quad)];
            h8 d1 = *(const h8*)&Vi[cur][swz8(vr_, quad + 4)];
            __builtin_amdgcn_s_setprio(1);
            Ovr[dt] = MFMA_F16(pa0, b0, Ovr[dt], 0, 0, 0);
            Ovr[dt] = MFMA_F16(pa1, b1, Ovr[dt], 0, 0, 0);
            Ovi[dt] = MFMA_F16(pa0, d0, Ovi[dt], 0, 0, 0);
            Ovi[dt] = MFMA_F16(pa1, d1, Ovi[dt], 0, 0, 0);
            __builtin_amdgcn_s_setprio(0);
        }

        __syncthreads();    // buf cur consumed; buf cur^1 fully written
    }

    {
        // finish L: reduce partials across the 16 m-lanes
        #pragma unroll
        for (int r = 0; r < 4; ++r) {
            float x = Lp[r];
            x += __shfl_xor(x, 1);
            x += __shfl_xor(x, 2);
            x += __shfl_xor(x, 4);
            x += __shfl_xor(x, 8);
            Lp[r] = x;
        }
        u16* Dr = br ? o2r : o1r;
        u16* Di = br ? o2i : o1i;
        float inv[4];
        #pragma unroll
        for (int r = 0; r < 4; ++r) inv[r] = 1.f / Lp[r];
        #pragma unroll
        for (int dt = 0; dt < 4; ++dt) {
            #pragma unroll
            for (int r = 0; r < 4; ++r) {
                int q = wr * 16 + quad * 4 + r;
                Dr[qbase + q * 64 + dt * 16 + m] = f2h(Ovr[dt][r] * inv[r]);
                Di[qbase + q * 64 + dt * 16 + m] = f2h(Ovi[dt][r] * inv[r]);
            }
        }
    }
}

// ---------------------------------------------------------------------------
// Kernel 3: MFMA epilogue (unchanged).
// ---------------------------------------------------------------------------
__global__ __launch_bounds__(256) void epi_kernel(
    const u16* __restrict__ o1r, const u16* __restrict__ o1i,
    const u16* __restrict__ o2r, const u16* __restrict__ o2i,
    const float* __restrict__ out_gr, const float* __restrict__ out_gi,
    const float* __restrict__ subw,
    const float* __restrict__ owr, const float* __restrict__ owi,
    const float* __restrict__ obr, const float* __restrict__ obi,
    float* __restrict__ out_r, float* __restrict__ out_i)
{
    __shared__ __align__(16) u16 L1r[16][64], L1i[16][64];
    __shared__ __align__(16) u16 L2r[16][64], L2i[16][64];
    __shared__ __align__(16) u16 Xr[16][PIT], Xi[16][PIT];

    const int t = threadIdx.x;
    const int rowbase = blockIdx.x * 16;

    // ---- stage o1/o2 (coalesced 8B loads) ----
    {
        int r = t >> 4, c4 = (t & 15) * 4;
        size_t gi = (size_t)(rowbase + r) * 64 + c4;
        *(us4v*)&L1r[r][c4] = *(const us4v*)(o1r + gi);
        *(us4v*)&L1i[r][c4] = *(const us4v*)(o1i + gi);
        *(us4v*)&L2r[r][c4] = *(const us4v*)(o2r + gi);
        *(us4v*)&L2i[r][c4] = *(const us4v*)(o2i + gi);
    }
    __syncthreads();

    // ---- RMS (joint over o1,o2 = all 128 interleaved cols) + x ----
    {
        int r = t >> 4, c4 = (t & 15) * 4;
        float ss = 0.f;
        #pragma unroll
        for (int j = 0; j < 4; ++j) {
            float a = h2f(L1r[r][c4 + j]), b = h2f(L1i[r][c4 + j]);
            float c = h2f(L2r[r][c4 + j]), d = h2f(L2i[r][c4 + j]);
            ss += a * a + b * b + c * c + d * d;
        }
        ss += __shfl_xor(ss, 1);
        ss += __shfl_xor(ss, 2);
        ss += __shfl_xor(ss, 4);
        ss += __shfl_xor(ss, 8);
        float inv = 1.f / sqrtf(ss * (1.f / 128.f) + 1e-5f);

        float4 g_r = *(const float4*)(out_gr + (size_t)(rowbase + r) * 64 + c4);
        float4 g_i = *(const float4*)(out_gi + (size_t)(rowbase + r) * 64 + c4);
        const float* grv = (const float*)&g_r;
        const float* giv = (const float*)&g_i;

        us4v xrp, xip;
        #pragma unroll
        for (int j = 0; j < 4; ++j) {
            int c = c4 + j;
            int s = c >> 1;
            float cr_ = (c & 1) ? h2f(L2r[r][s]) : h2f(L1r[r][s]);
            float ci_ = (c & 1) ? h2f(L2i[r][s]) : h2f(L1i[r][s]);
            float sw = subw[c];
            float ar_ = cr_ * inv * sw;
            float ai_ = ci_ * inv * sw;
            xrp[j] = f2h(grv[j] * ar_ - giv[j] * ai_);
            xip[j] = f2h(grv[j] * ai_ + giv[j] * ar_);
        }
        *(us4v*)&Xr[r][c4] = xrp;
        *(us4v*)&Xi[r][c4] = xip;
    }
    __syncthreads();

    // ---- out-projection: wave w = n-tile w ----
    const int wv = t >> 6, l = t & 63;
    const int quad = l >> 4, m16 = l & 15;
    const int c0 = quad * 8;

    h8 Ar0 = *(const h8*)&Xr[m16][c0];
    h8 Ar1 = *(const h8*)&Xr[m16][32 + c0];
    h8 Ai0 = *(const h8*)&Xi[m16][c0];
    h8 Ai1 = *(const h8*)&Xi[m16][32 + c0];
    h8 nAi0 = neg_h8(Ai0), nAi1 = neg_h8(Ai1);

    const int c = wv * 16 + m16;
    const float* wrp = owr + c * 64;
    const float* wip = owi + c * 64;
    h8 Br0 = pack8h(wrp + c0), Br1 = pack8h(wrp + 32 + c0);
    h8 Bi0 = pack8h(wip + c0), Bi1 = pack8h(wip + 32 + c0);

    f4 Cr = (f4)0.f, Ci = (f4)0.f;
    Cr = MFMA_F16(Ar0,  Br0, Cr, 0, 0, 0);
    Cr = MFMA_F16(Ar1,  Br1, Cr, 0, 0, 0);
    Cr = MFMA_F16(nAi0, Bi0, Cr, 0, 0, 0);
    Cr = MFMA_F16(nAi1, Bi1, Cr, 0, 0, 0);
    Ci = MFMA_F16(Ar0,  Bi0, Ci, 0, 0, 0);
    Ci = MFMA_F16(Ar1,  Bi1, Ci, 0, 0, 0);
    Ci = MFMA_F16(Ai0,  Br0, Ci, 0, 0, 0);
    Ci = MFMA_F16(Ai1,  Br1, Ci, 0, 0, 0);

    float br_ = obr[c], bi_ = obi[c];
    #pragma unroll
    for (int r = 0; r < 4; ++r) {
        size_t g = (size_t)(rowbase + quad * 4 + r) * 64 + c;
        out_r[g] = Cr[r] + br_;
        out_i[g] = Ci[r] + bi_;
    }
}

// ---------------------------------------------------------------------------
extern "C" void kernel_launch(void* const* d_in, const int* in_sizes, int n_in,
                              void* d_out, int out_size, void* d_ws, size_t ws_size,
                              hipStream_t stream)
{
    (void)in_sizes; (void)n_in; (void)out_size; (void)ws_size;

    float* out    = (float*)d_out;
    float* out_r  = out;
    float* out_i  = out + (size_t)NTOT;
    float* out_gr = out + 2 * (size_t)NTOT;
    float* out_gi = out + 3 * (size_t)NTOT;

    // workspace layout (f16 only), 24 MB total
    char* w = (char*)d_ws;
    const size_t N = (size_t)NTOT;
    u16* q1r = (u16*)w; w += N * 2;
    u16* q1i = (u16*)w; w += N * 2;
    u16* q2r = (u16*)w; w += N * 2;
    u16* q2i = (u16*)w; w += N * 2;
    u16* kpr = (u16*)w; w += N * 2;
    u16* kpi = (u16*)w; w += N * 2;
    u16* vtr = (u16*)w; w += N * 2;   // [h][d][s]
    u16* vti = (u16*)w; w += N * 2;   // [h][d][s]
    u16* o1r = (u16*)w; w += N * 2;
    u16* o1i = (u16*)w; w += N * 2;
    u16* o2r = (u16*)w; w += N * 2;
    u16* o2i = (u16*)w; w += N * 2;

    proj_kernel<<<dim3(1024), dim3(256), 0, stream>>>(
        (const float*)d_in[0], (const float*)d_in[1],
        (const float*)d_in[2], (const float*)d_in[3],
        (const float*)d_in[4], (const float*)d_in[5],
        (const float*)d_in[6], (const float*)d_in[7],
        (const float*)d_in[8], (const float*)d_in[9],
        (const float*)d_in[10], (const float*)d_in[11],
        (const float*)d_in[12], (const float*)d_in[13],
        (const float*)d_in[14], (const float*)d_in[15],
        (const float*)d_in[16], (const float*)d_in[17],
        (const float*)d_in[18], (const float*)d_in[19],
        (const float*)d_in[20], (const float*)d_in[21],
        (const float*)d_in[22], (const float*)d_in[23],
        (const float*)d_in[24], (const float*)d_in[25],
        q1r, q1i, q2r, q2i, kpr, kpi, vtr, vti, out_gr, out_gi);

    attn_kernel<<<dim3(SQ / 64, 1, NH), dim3(512), 0, stream>>>(
        q1r, q1i, q2r, q2i, kpr, kpi, vtr, vti, o1r, o1i, o2r, o2i);

    epi_kernel<<<dim3(1024), dim3(256), 0, stream>>>(
        o1r, o1i, o2r, o2i, out_gr, out_gi,
        (const float*)d_in[34], (const float*)d_in[26], (const float*)d_in[27],
        (const float*)d_in[28], (const float*)d_in[29],
        out_r, out_i);
}

// Round 6
// 236.077 us; speedup vs baseline: 1.7236x; 1.0496x over previous
//
#include <hip/hip_runtime.h>
#include <hip/hip_bf16.h>

#define NH 8
#define SQ 2048
#define HD 64
#define NTOT (NH * SQ * HD)   // 1048576

typedef unsigned short u16;
typedef unsigned int u32;
typedef __attribute__((ext_vector_type(8))) unsigned short us8;
typedef __attribute__((ext_vector_type(4))) unsigned short us4v;
typedef __attribute__((ext_vector_type(8))) _Float16 h8;   // MFMA f16 A/B fragment
typedef __attribute__((ext_vector_type(4))) float f4;      // MFMA C/D fragment
typedef __attribute__((ext_vector_type(4))) u32 u4;

#define MFMA_F16 __builtin_amdgcn_mfma_f32_16x16x32_f16

__device__ __forceinline__ u16 f2h(float f) {
    union { _Float16 h; u16 u; } c; c.h = (_Float16)f; return c.u;
}
__device__ __forceinline__ float h2f(u16 u) {
    union { _Float16 h; u16 u; } c; c.u = u; return (float)c.h;
}
__device__ __forceinline__ h8 neg_h8(h8 a) {
    union { h8 h; u4 u; } c; c.h = a;
    c.u ^= 0x80008000u;
    return c.h;
}
// 8 contiguous f32 -> f16x8 fragment (two float4 loads, hw cvt)
__device__ __forceinline__ h8 pack8h(const float* p) {
    float4 a = ((const float4*)p)[0];
    float4 b = ((const float4*)p)[1];
    h8 r;
    r[0] = (_Float16)a.x; r[1] = (_Float16)a.y; r[2] = (_Float16)a.z; r[3] = (_Float16)a.w;
    r[4] = (_Float16)b.x; r[5] = (_Float16)b.y; r[6] = (_Float16)b.z; r[7] = (_Float16)b.w;
    return r;
}

// T2 swizzle: pitch 64 u16 (128B rows), 16B-chunk index XOR'd with row&7.
__device__ __forceinline__ int swz8(int row, int chunk) {   // u16 offset of 8-u16 chunk
    return row * 64 + ((chunk ^ (row & 7)) << 3);
}

struct Afrag { h8 r0, r1, i0, i1, ni0, ni1; };

// ---------------------------------------------------------------------------
// Prep kernels: pre-pack weights into MFMA B-fragment order so the hot
// kernels read them as coalesced 16B/lane us8 (kills the 16-line scatter of
// per-lane pack8h row loads — the R3-proven latency poison).
// Plane layout: plane p = [half(2)][lane(64)][8 u16]  (1024 u16 = 2KB).
// prep1 (before proj, into o1r region): qwr 0-7, qwi 8-15, kwr 16-19,
//   kwi 20-23, vwr 24-27, vwi 28-31, gwr 32-35, gwi 36-39.
// prep2 (after attn, into q1r region): owr 0-3, owi 4-7.
// ---------------------------------------------------------------------------
__global__ __launch_bounds__(128) void prep1_kernel(
    const float* __restrict__ qwr, const float* __restrict__ qwi,
    const float* __restrict__ kwr, const float* __restrict__ kwi,
    const float* __restrict__ vwr, const float* __restrict__ vwi,
    const float* __restrict__ gwr, const float* __restrict__ gwi,
    u16* __restrict__ pk)
{
    const int b = blockIdx.x;
    const float* W; int nt;
    if (b < 8)       { W = qwr; nt = b; }
    else if (b < 16) { W = qwi; nt = b - 8; }
    else if (b < 20) { W = kwr; nt = b - 16; }
    else if (b < 24) { W = kwi; nt = b - 20; }
    else if (b < 28) { W = vwr; nt = b - 24; }
    else if (b < 32) { W = vwi; nt = b - 28; }
    else if (b < 36) { W = gwr; nt = b - 32; }
    else             { W = gwi; nt = b - 36; }
    const int t = threadIdx.x, hf = t >> 6, l = t & 63;
    const int quad = l >> 4, m16 = l & 15;
    h8 v = pack8h(W + (nt * 16 + m16) * 64 + hf * 32 + quad * 8);
    *(h8*)(pk + b * 1024 + hf * 512 + l * 8) = v;
}

__global__ __launch_bounds__(128) void prep2_kernel(
    const float* __restrict__ owr, const float* __restrict__ owi,
    u16* __restrict__ pk)
{
    const int b = blockIdx.x;
    const float* W = (b < 4) ? owr : owi;
    const int nt = b & 3;
    const int t = threadIdx.x, hf = t >> 6, l = t & 63;
    const int quad = l >> 4, m16 = l & 15;
    h8 v = pack8h(W + (nt * 16 + m16) * 64 + hf * 32 + quad * 8);
    *(h8*)(pk + b * 1024 + hf * 512 + l * 8) = v;
}

// ---------------------------------------------------------------------------
// Kernel 1: MFMA complex projections.
//   Round-14: weights read from packed fragments (coalesced us8); inputs
//   staged through 12KB swz8 LDS (coalesced float4 -> f16 -> ds_read_b128).
//   All 16-line scattered fragment loads eliminated.
// ---------------------------------------------------------------------------
__global__ __launch_bounds__(256) void proj_kernel(
    const float* __restrict__ q_r, const float* __restrict__ q_i,
    const float* __restrict__ k_r, const float* __restrict__ k_i,
    const float* __restrict__ v_r, const float* __restrict__ v_i,
    const float* __restrict__ pe_q_r, const float* __restrict__ pe_q_i,
    const float* __restrict__ pe_k_r, const float* __restrict__ pe_k_i,
    const u16* __restrict__ pk,
    const float* __restrict__ qbr, const float* __restrict__ qbi,
    const float* __restrict__ kbr, const float* __restrict__ kbi,
    const float* __restrict__ vbr, const float* __restrict__ vbi,
    const float* __restrict__ gbr, const float* __restrict__ gbi,
    u16* __restrict__ q1r, u16* __restrict__ q1i,
    u16* __restrict__ q2r, u16* __restrict__ q2i,
    u16* __restrict__ kpr, u16* __restrict__ kpi,
    u16* __restrict__ vtr, u16* __restrict__ vti,
    float* __restrict__ out_gr, float* __restrict__ out_gi)
{
    __shared__ __align__(16) u16 Sqr[16 * 64], Sqi[16 * 64];
    __shared__ __align__(16) u16 Skr[16 * 64], Ski[16 * 64];
    __shared__ __align__(16) u16 Svr[16 * 64], Svi[16 * 64];

    const int t = threadIdx.x;
    const int wv = t >> 6, l = t & 63;
    const int quad = l >> 4, m16 = l & 15;
    const int rowbase = blockIdx.x * 16;
    const int h = rowbase >> 11;
    const int l8 = l * 8;

    // ---- stage 6 input tiles: coalesced float4 -> f16 -> swz8 LDS ----
    {
        const int r = t >> 4, c4 = (t & 15) * 4;
        const int off = swz8(r, c4 >> 3) + (c4 & 7);
        const size_t gi = (size_t)(rowbase + r) * 64 + c4;
        auto stage = [&](const float* src, u16* dst) {
            float4 v = *(const float4*)(src + gi);
            us4v p;
            p[0] = f2h(v.x); p[1] = f2h(v.y); p[2] = f2h(v.z); p[3] = f2h(v.w);
            *(us4v*)&dst[off] = p;
        };
        stage(q_r, Sqr); stage(q_i, Sqi);
        stage(k_r, Skr); stage(k_i, Ski);
        stage(v_r, Svr); stage(v_i, Svi);
    }
    __syncthreads();

    auto loadA = [&](const u16* Sr, const u16* Si) {
        Afrag a;
        a.r0 = *(const h8*)&Sr[swz8(m16, quad)];
        a.r1 = *(const h8*)&Sr[swz8(m16, quad + 4)];
        a.i0 = *(const h8*)&Si[swz8(m16, quad)];
        a.i1 = *(const h8*)&Si[swz8(m16, quad + 4)];
        a.ni0 = neg_h8(a.i0);
        a.ni1 = neg_h8(a.i1);
        return a;
    };

    // packed-weight ctile: planes at pk + planeBase*1024
    auto ctile = [&](const Afrag& A, int planeR, int planeI, f4& Cr, f4& Ci) {
        const u16* pR = pk + planeR * 1024;
        const u16* pI = pk + planeI * 1024;
        h8 Br0 = *(const h8*)(pR + l8);
        h8 Br1 = *(const h8*)(pR + 512 + l8);
        h8 Bi0 = *(const h8*)(pI + l8);
        h8 Bi1 = *(const h8*)(pI + 512 + l8);
        Cr = (f4)0.f; Ci = (f4)0.f;
        Cr = MFMA_F16(A.r0,  Br0, Cr, 0, 0, 0);
        Cr = MFMA_F16(A.r1,  Br1, Cr, 0, 0, 0);
        Cr = MFMA_F16(A.ni0, Bi0, Cr, 0, 0, 0);
        Cr = MFMA_F16(A.ni1, Bi1, Cr, 0, 0, 0);
        Ci = MFMA_F16(A.r0,  Bi0, Ci, 0, 0, 0);
        Ci = MFMA_F16(A.r1,  Bi1, Ci, 0, 0, 0);
        Ci = MFMA_F16(A.i0,  Br0, Ci, 0, 0, 0);
        Ci = MFMA_F16(A.i1,  Br1, Ci, 0, 0, 0);
    };

    auto qtile = [&](const Afrag& A, int nt) {
        f4 Cr, Ci;
        ctile(A, nt, 8 + nt, Cr, Ci);
        int c = nt * 16 + m16;
        float br = qbr[c], bi = qbi[c];
        int dd = c >> 1, pc = c & 63;
        u16* dR = (c & 1) ? q2r : q1r;
        u16* dI = (c & 1) ? q2i : q1i;
        #pragma unroll
        for (int r = 0; r < 4; ++r) {
            int g = rowbase + quad * 4 + r;
            dR[g * 64 + dd] = f2h(Cr[r] + br + pe_q_r[g * 64 + pc]);
            dI[g * 64 + dd] = f2h(Ci[r] + bi + pe_q_i[g * 64 + pc]);
        }
    };
    auto ktile = [&](const Afrag& A, int nt) {
        f4 Cr, Ci;
        ctile(A, 16 + nt, 20 + nt, Cr, Ci);
        int c = nt * 16 + m16;
        float br = kbr[c], bi = kbi[c];
        #pragma unroll
        for (int r = 0; r < 4; ++r) {
            int g = rowbase + quad * 4 + r;
            kpr[g * 64 + c] = f2h(Cr[r] + br + pe_k_r[g * 64 + c]);
            kpi[g * 64 + c] = f2h(Ci[r] + bi + pe_k_i[g * 64 + c]);
        }
    };
    auto vtile = [&](const Afrag& A, int nt) {
        f4 Cr, Ci;
        ctile(A, 24 + nt, 28 + nt, Cr, Ci);
        int c = nt * 16 + m16;
        float br = vbr[c], bi = vbi[c];
        int s0 = (rowbase & 2047) + quad * 4;
        size_t tix = (size_t)(h * 64 + c) * 2048 + s0;
        us4v pr, pi;
        #pragma unroll
        for (int r = 0; r < 4; ++r) {
            pr[r] = f2h(Cr[r] + br);
            pi[r] = f2h(Ci[r] + bi);
        }
        *(us4v*)&vtr[tix] = pr;
        *(us4v*)&vti[tix] = pi;
    };
    auto gtile = [&](const Afrag& A, int nt) {
        f4 Cr, Ci;
        ctile(A, 32 + nt, 36 + nt, Cr, Ci);
        int c = nt * 16 + m16;
        float br = gbr[c], bi = gbi[c];
        #pragma unroll
        for (int r = 0; r < 4; ++r) {
            int g = rowbase + quad * 4 + r;
            out_gr[g * 64 + c] = Cr[r] + br;
            out_gi[g * 64 + c] = Ci[r] + bi;
        }
    };

    if (wv == 0) {
        Afrag Aq = loadA(Sqr, Sqi);
        qtile(Aq, 0); qtile(Aq, 1); qtile(Aq, 2); qtile(Aq, 3); qtile(Aq, 4);
    } else if (wv == 1) {
        Afrag Aq = loadA(Sqr, Sqi);
        qtile(Aq, 5); qtile(Aq, 6); qtile(Aq, 7);
        gtile(Aq, 0); gtile(Aq, 1);
    } else if (wv == 2) {
        Afrag Ak = loadA(Skr, Ski);
        ktile(Ak, 0); ktile(Ak, 1); ktile(Ak, 2); ktile(Ak, 3);
        Afrag Aq = loadA(Sqr, Sqi);
        gtile(Aq, 2);
    } else {
        Afrag Av = loadA(Svr, Svi);
        vtile(Av, 0); vtile(Av, 1); vtile(Av, 2); vtile(Av, 3);
        Afrag Aq = loadA(Sqr, Sqi);
        gtile(Aq, 3);
    }
}

// ---------------------------------------------------------------------------
// Kernel 2: MFMA flash attention (unchanged from R5: merged branches,
// 512-thread block, dbuf K/V, one barrier/kt; 87.7us verified).
// ---------------------------------------------------------------------------
__global__ __launch_bounds__(512, 2) void attn_kernel(
    const u16* __restrict__ q1r, const u16* __restrict__ q1i,
    const u16* __restrict__ q2r, const u16* __restrict__ q2i,
    const u16* __restrict__ kpr, const u16* __restrict__ kpi,
    const u16* __restrict__ vtr, const u16* __restrict__ vti,
    u16* __restrict__ o1r, u16* __restrict__ o1i,
    u16* __restrict__ o2r, u16* __restrict__ o2i)
{
    __shared__ __align__(16) u16 Kr[2][64 * 64], Ki[2][64 * 64];
    __shared__ __align__(16) u16 Vr[2][64 * 64], Vi[2][64 * 64];
    __shared__ __align__(16) u16 Pb[128 * 64];

    const int t  = threadIdx.x;      // 0..511
    const int qt = blockIdx.x;
    const int h  = blockIdx.z;

    const int wq   = t >> 6;         // wave 0..7
    const int br   = wq >> 2;        // branch
    const int wr   = wq & 3;         // 16-row block within the 64-row q tile
    const int l    = t & 63;
    const int quad = l >> 4;
    const int m    = l & 15;

    const u16* Qsr = br ? q2r : q1r;
    const u16* Qsi = br ? q2i : q1i;
    const int hbase = h * SQ * 64;
    const int qbase = hbase + qt * 64 * 64;
    const int vbase = h * 64 * SQ;

    const u16* qrr = Qsr + qbase + (wr * 16 + m) * 64;
    const u16* qri = Qsi + qbase + (wr * 16 + m) * 64;
    h8 Qr0 = *(const h8*)(qrr + quad * 8);
    h8 Qr1 = *(const h8*)(qrr + 32 + quad * 8);
    h8 Qi0 = *(const h8*)(qri + quad * 8);
    h8 Qi1 = *(const h8*)(qri + 32 + quad * 8);
    h8 nQr0 = neg_h8(Qr0);
    h8 nQr1 = neg_h8(Qr1);

    // ---- staging: 512 threads cover one 64x64 u16 tile per array ----
    const int sr0 = t >> 3;           // row 0..63
    const int sc  = t & 7;            // 8-u16 chunk
    us8 rK, rC, rV, rW;

    auto issue = [&](int kt) {
        const int kb = hbase + kt * 4096;
        const int vb = vbase + kt * 64;
        const int sc8 = sc * 8;
        rK = *(const us8*)(kpr + kb + sr0 * 64 + sc8);
        rC = *(const us8*)(kpi + kb + sr0 * 64 + sc8);
        rV = *(const us8*)(vtr + vb + sr0 * SQ + sc8);
        rW = *(const us8*)(vti + vb + sr0 * SQ + sc8);
    };
    auto commit = [&](int b) {
        const int o = swz8(sr0, sc);
        *(us8*)&Kr[b][o] = rK;
        *(us8*)&Ki[b][o] = rC;
        *(us8*)&Vr[b][o] = rV;
        *(us8*)&Vi[b][o] = rW;
    };

    float mreg[4], Lp[4];
    #pragma unroll
    for (int r = 0; r < 4; ++r) { mreg[r] = -1e30f; Lp[r] = 0.f; }
    f4 Ovr[4], Ovi[4];
    #pragma unroll
    for (int d = 0; d < 4; ++d) { Ovr[d] = (f4)0.f; Ovi[d] = (f4)0.f; }

    // prologue: tile0 -> buf0; loads for tile1 in flight
    issue(0);
    commit(0);          // compiler inserts vmcnt wait
    issue(1);
    __syncthreads();

    for (int kt = 0; kt < 32; ++kt) {
        const int cur = kt & 1;
        if (kt < 31) commit(cur ^ 1);    // tile kt+1 regs -> other buffer
        if (kt < 30) issue(kt + 2);      // loads in flight across this iter

        // ---- QK^T (complex magnitude scores) ----
        float sv[4][4];
        #pragma unroll
        for (int nt = 0; nt < 4; ++nt) {
            const int kr = nt * 16 + m;
            h8 k0 = *(const h8*)&Kr[cur][swz8(kr, quad)];
            h8 k1 = *(const h8*)&Kr[cur][swz8(kr, quad + 4)];
            h8 c0 = *(const h8*)&Ki[cur][swz8(kr, quad)];
            h8 c1 = *(const h8*)&Ki[cur][swz8(kr, quad + 4)];
            f4 ar = (f4)0.f, ai = (f4)0.f;
            __builtin_amdgcn_s_setprio(1);
            ar = MFMA_F16(Qr0, k0, ar, 0, 0, 0);
            ar = MFMA_F16(Qr1, k1, ar, 0, 0, 0);
            ar = MFMA_F16(Qi0, c0, ar, 0, 0, 0);
            ar = MFMA_F16(Qi1, c1, ar, 0, 0, 0);
            ai = MFMA_F16(Qi0, k0, ai, 0, 0, 0);
            ai = MFMA_F16(Qi1, k1, ai, 0, 0, 0);
            ai = MFMA_F16(nQr0, c0, ai, 0, 0, 0);
            ai = MFMA_F16(nQr1, c1, ai, 0, 0, 0);
            __builtin_amdgcn_s_setprio(0);
            #pragma unroll
            for (int r = 0; r < 4; ++r)
                sv[nt][r] = __builtin_amdgcn_sqrtf(ar[r] * ar[r] + ai[r] * ai[r] + 1e-8f) * 0.125f;
        }

        // ---- exact per-row tile max (16-lane reduce) ----
        float rv[4];
        #pragma unroll
        for (int r = 0; r < 4; ++r) {
            float x = fmaxf(fmaxf(sv[0][r], sv[1][r]), fmaxf(sv[2][r], sv[3][r]));
            x = fmaxf(x, __shfl_xor(x, 1));
            x = fmaxf(x, __shfl_xor(x, 2));
            x = fmaxf(x, __shfl_xor(x, 4));
            x = fmaxf(x, __shfl_xor(x, 8));
            rv[r] = x;
        }

        // ---- T13 defer-max: rescale only when a row grows past slack ----
        bool need = (rv[0] > mreg[0] + 8.f) | (rv[1] > mreg[1] + 8.f) |
                    (rv[2] > mreg[2] + 8.f) | (rv[3] > mreg[3] + 8.f);
        if (__any(need)) {
            #pragma unroll
            for (int r = 0; r < 4; ++r) {
                float mn = fmaxf(mreg[r], rv[r]);
                float al = __expf(mreg[r] - mn);
                mreg[r] = mn;
                Lp[r] *= al;
                #pragma unroll
                for (int dtr = 0; dtr < 4; ++dtr) { Ovr[dtr][r] *= al; Ovi[dtr][r] *= al; }
            }
        }

        // ---- P = exp(s - m)  (f32 row-sum partials; f16 to LDS for MFMA) ----
        #pragma unroll
        for (int r = 0; r < 4; ++r) {
            const int prow = wq * 16 + quad * 4 + r;
            #pragma unroll
            for (int nt = 0; nt < 4; ++nt) {
                float p = __expf(sv[nt][r] - mreg[r]);
                Lp[r] += p;
                const int col = nt * 16 + m;
                Pb[swz8(prow, col >> 3) + (col & 7)] = f2h(p);
            }
        }

        const int qrow = wq * 16 + m;
        h8 pa0 = *(const h8*)&Pb[swz8(qrow, quad)];
        h8 pa1 = *(const h8*)&Pb[swz8(qrow, quad + 4)];

        // ---- PV ----
        #pragma unroll
        for (int dt = 0; dt < 4; ++dt) {
            const int vr_ = dt * 16 + m;
            h8 b0 = *(const h8*)&Vr[cur][swz8(vr_, quad)];
            h8 b1 = *(const h8*)&Vr[cur][swz8(vr_, quad + 4)];
            h8 d0 = *(const h8*)&Vi[cur][swz8(vr_, quad)];
            h8 d1 = *(const h8*)&Vi[cur][swz8(vr_, quad + 4)];
            __builtin_amdgcn_s_setprio(1);
            Ovr[dt] = MFMA_F16(pa0, b0, Ovr[dt], 0, 0, 0);
            Ovr[dt] = MFMA_F16(pa1, b1, Ovr[dt], 0, 0, 0);
            Ovi[dt] = MFMA_F16(pa0, d0, Ovi[dt], 0, 0, 0);
            Ovi[dt] = MFMA_F16(pa1, d1, Ovi[dt], 0, 0, 0);
            __builtin_amdgcn_s_setprio(0);
        }

        __syncthreads();    // buf cur consumed; buf cur^1 fully written
    }

    {
        // finish L: reduce partials across the 16 m-lanes
        #pragma unroll
        for (int r = 0; r < 4; ++r) {
            float x = Lp[r];
            x += __shfl_xor(x, 1);
            x += __shfl_xor(x, 2);
            x += __shfl_xor(x, 4);
            x += __shfl_xor(x, 8);
            Lp[r] = x;
        }
        u16* Dr = br ? o2r : o1r;
        u16* Di = br ? o2i : o1i;
        float inv[4];
        #pragma unroll
        for (int r = 0; r < 4; ++r) inv[r] = 1.f / Lp[r];
        #pragma unroll
        for (int dt = 0; dt < 4; ++dt) {
            #pragma unroll
            for (int r = 0; r < 4; ++r) {
                int q = wr * 16 + quad * 4 + r;
                Dr[qbase + q * 64 + dt * 16 + m] = f2h(Ovr[dt][r] * inv[r]);
                Di[qbase + q * 64 + dt * 16 + m] = f2h(Ovi[dt][r] * inv[r]);
            }
        }
    }
}

// ---------------------------------------------------------------------------
// Kernel 3: MFMA epilogue.  Round-14: packed ow fragments (coalesced us8)
// + Xr/Xi on swz8 64-pitch layout.
// ---------------------------------------------------------------------------
__global__ __launch_bounds__(256) void epi_kernel(
    const u16* __restrict__ o1r, const u16* __restrict__ o1i,
    const u16* __restrict__ o2r, const u16* __restrict__ o2i,
    const float* __restrict__ out_gr, const float* __restrict__ out_gi,
    const float* __restrict__ subw,
    const u16* __restrict__ pko,
    const float* __restrict__ obr, const float* __restrict__ obi,
    float* __restrict__ out_r, float* __restrict__ out_i)
{
    __shared__ __align__(16) u16 L1r[16][64], L1i[16][64];
    __shared__ __align__(16) u16 L2r[16][64], L2i[16][64];
    __shared__ __align__(16) u16 Xr[16 * 64], Xi[16 * 64];

    const int t = threadIdx.x;
    const int rowbase = blockIdx.x * 16;

    // ---- stage o1/o2 (coalesced 8B loads) ----
    {
        int r = t >> 4, c4 = (t & 15) * 4;
        size_t gi = (size_t)(rowbase + r) * 64 + c4;
        *(us4v*)&L1r[r][c4] = *(const us4v*)(o1r + gi);
        *(us4v*)&L1i[r][c4] = *(const us4v*)(o1i + gi);
        *(us4v*)&L2r[r][c4] = *(const us4v*)(o2r + gi);
        *(us4v*)&L2i[r][c4] = *(const us4v*)(o2i + gi);
    }
    __syncthreads();

    // ---- RMS (joint over o1,o2 = all 128 interleaved cols) + x ----
    {
        int r = t >> 4, c4 = (t & 15) * 4;
        float ss = 0.f;
        #pragma unroll
        for (int j = 0; j < 4; ++j) {
            float a = h2f(L1r[r][c4 + j]), b = h2f(L1i[r][c4 + j]);
            float c = h2f(L2r[r][c4 + j]), d = h2f(L2i[r][c4 + j]);
            ss += a * a + b * b + c * c + d * d;
        }
        ss += __shfl_xor(ss, 1);
        ss += __shfl_xor(ss, 2);
        ss += __shfl_xor(ss, 4);
        ss += __shfl_xor(ss, 8);
        float inv = 1.f / sqrtf(ss * (1.f / 128.f) + 1e-5f);

        float4 g_r = *(const float4*)(out_gr + (size_t)(rowbase + r) * 64 + c4);
        float4 g_i = *(const float4*)(out_gi + (size_t)(rowbase + r) * 64 + c4);
        const float* grv = (const float*)&g_r;
        const float* giv = (const float*)&g_i;

        us4v xrp, xip;
        #pragma unroll
        for (int j = 0; j < 4; ++j) {
            int c = c4 + j;
            int s = c >> 1;
            float cr_ = (c & 1) ? h2f(L2r[r][s]) : h2f(L1r[r][s]);
            float ci_ = (c & 1) ? h2f(L2i[r][s]) : h2f(L1i[r][s]);
            float sw = subw[c];
            float ar_ = cr_ * inv * sw;
            float ai_ = ci_ * inv * sw;
            xrp[j] = f2h(grv[j] * ar_ - giv[j] * ai_);
            xip[j] = f2h(grv[j] * ai_ + giv[j] * ar_);
        }
        const int off = swz8(r, c4 >> 3) + (c4 & 7);
        *(us4v*)&Xr[off] = xrp;
        *(us4v*)&Xi[off] = xip;
    }
    __syncthreads();

    // ---- out-projection: wave w = n-tile w ----
    const int wv = t >> 6, l = t & 63;
    const int quad = l >> 4, m16 = l & 15;
    const int l8 = l * 8;

    h8 Ar0 = *(const h8*)&Xr[swz8(m16, quad)];
    h8 Ar1 = *(const h8*)&Xr[swz8(m16, quad + 4)];
    h8 Ai0 = *(const h8*)&Xi[swz8(m16, quad)];
    h8 Ai1 = *(const h8*)&Xi[swz8(m16, quad + 4)];
    h8 nAi0 = neg_h8(Ai0), nAi1 = neg_h8(Ai1);

    const int c = wv * 16 + m16;
    h8 Br0 = *(const h8*)(pko + wv * 1024 + l8);
    h8 Br1 = *(const h8*)(pko + wv * 1024 + 512 + l8);
    h8 Bi0 = *(const h8*)(pko + 4096 + wv * 1024 + l8);
    h8 Bi1 = *(const h8*)(pko + 4096 + wv * 1024 + 512 + l8);

    f4 Cr = (f4)0.f, Ci = (f4)0.f;
    Cr = MFMA_F16(Ar0,  Br0, Cr, 0, 0, 0);
    Cr = MFMA_F16(Ar1,  Br1, Cr, 0, 0, 0);
    Cr = MFMA_F16(nAi0, Bi0, Cr, 0, 0, 0);
    Cr = MFMA_F16(nAi1, Bi1, Cr, 0, 0, 0);
    Ci = MFMA_F16(Ar0,  Bi0, Ci, 0, 0, 0);
    Ci = MFMA_F16(Ar1,  Bi1, Ci, 0, 0, 0);
    Ci = MFMA_F16(Ai0,  Br0, Ci, 0, 0, 0);
    Ci = MFMA_F16(Ai1,  Br1, Ci, 0, 0, 0);

    float br_ = obr[c], bi_ = obi[c];
    #pragma unroll
    for (int r = 0; r < 4; ++r) {
        size_t g = (size_t)(rowbase + quad * 4 + r) * 64 + c;
        out_r[g] = Cr[r] + br_;
        out_i[g] = Ci[r] + bi_;
    }
}

// ---------------------------------------------------------------------------
extern "C" void kernel_launch(void* const* d_in, const int* in_sizes, int n_in,
                              void* d_out, int out_size, void* d_ws, size_t ws_size,
                              hipStream_t stream)
{
    (void)in_sizes; (void)n_in; (void)out_size; (void)ws_size;

    float* out    = (float*)d_out;
    float* out_r  = out;
    float* out_i  = out + (size_t)NTOT;
    float* out_gr = out + 2 * (size_t)NTOT;
    float* out_gi = out + 3 * (size_t)NTOT;

    // workspace layout (f16 only), 24 MB total
    char* w = (char*)d_ws;
    const size_t N = (size_t)NTOT;
    u16* q1r = (u16*)w; w += N * 2;
    u16* q1i = (u16*)w; w += N * 2;
    u16* q2r = (u16*)w; w += N * 2;
    u16* q2i = (u16*)w; w += N * 2;
    u16* kpr = (u16*)w; w += N * 2;
    u16* kpi = (u16*)w; w += N * 2;
    u16* vtr = (u16*)w; w += N * 2;   // [h][d][s]
    u16* vti = (u16*)w; w += N * 2;   // [h][d][s]
    u16* o1r = (u16*)w; w += N * 2;
    u16* o1i = (u16*)w; w += N * 2;
    u16* o2r = (u16*)w; w += N * 2;
    u16* o2i = (u16*)w; w += N * 2;

    // packed-weight scratch (aliased into dead regions):
    //  - proj weights (80KB) live in o1r space: written by prep1 BEFORE proj,
    //    consumed by proj, clobbered later by attn's o1r writes.  safe.
    //  - ow pack (16KB) lives in q1r space: written by prep2 AFTER attn (q1r
    //    dead by then), consumed by epi.  safe.
    u16* pk1 = o1r;
    u16* pk2 = q1r;

    prep1_kernel<<<dim3(40), dim3(128), 0, stream>>>(
        (const float*)d_in[10], (const float*)d_in[11],
        (const float*)d_in[14], (const float*)d_in[15],
        (const float*)d_in[18], (const float*)d_in[19],
        (const float*)d_in[22], (const float*)d_in[23],
        pk1);

    proj_kernel<<<dim3(1024), dim3(256), 0, stream>>>(
        (const float*)d_in[0], (const float*)d_in[1],
        (const float*)d_in[2], (const float*)d_in[3],
        (const float*)d_in[4], (const float*)d_in[5],
        (const float*)d_in[6], (const float*)d_in[7],
        (const float*)d_in[8], (const float*)d_in[9],
        pk1,
        (const float*)d_in[12], (const float*)d_in[13],
        (const float*)d_in[16], (const float*)d_in[17],
        (const float*)d_in[20], (const float*)d_in[21],
        (const float*)d_in[24], (const float*)d_in[25],
        q1r, q1i, q2r, q2i, kpr, kpi, vtr, vti, out_gr, out_gi);

    attn_kernel<<<dim3(SQ / 64, 1, NH), dim3(512), 0, stream>>>(
        q1r, q1i, q2r, q2i, kpr, kpi, vtr, vti, o1r, o1i, o2r, o2i);

    prep2_kernel<<<dim3(8), dim3(128), 0, stream>>>(
        (const float*)d_in[26], (const float*)d_in[27], pk2);

    epi_kernel<<<dim3(1024), dim3(256), 0, stream>>>(
        o1r, o1i, o2r, o2i, out_gr, out_gi,
        (const float*)d_in[34], pk2,
        (const float*)d_in[28], (const float*)d_in[29],
        out_r, out_i);
}